// Round 1
// baseline (577.446 us; speedup 1.0000x reference)
//
#include <hip/hip_runtime.h>

#define EPS 1e-5f
#define SLOPE 0.01f

// ---------------- CSR build ----------------

__global__ void deg_kernel(const int* __restrict__ dst, int* __restrict__ deg, int E) {
  int e = blockIdx.x * blockDim.x + threadIdx.x;
  if (e < E) atomicAdd(&deg[dst[e]], 1);
}

__global__ void scan1_kernel(const int* __restrict__ deg, int* __restrict__ rowptr,
                             int* __restrict__ bsum, int n) {
  __shared__ int s[256];
  int i = blockIdx.x * 256 + threadIdx.x;
  int v = (i < n) ? deg[i] : 0;
  s[threadIdx.x] = v;
  __syncthreads();
  for (int off = 1; off < 256; off <<= 1) {
    int t = (threadIdx.x >= off) ? s[threadIdx.x - off] : 0;
    __syncthreads();
    s[threadIdx.x] += t;
    __syncthreads();
  }
  if (i < n) rowptr[i] = s[threadIdx.x] - v;  // exclusive within block
  if (threadIdx.x == 255) bsum[blockIdx.x] = s[255];
}

__global__ void scan2_kernel(int* __restrict__ bsum, int nb) {
  __shared__ int s[512];
  int tid = threadIdx.x;
  int v = (tid < nb) ? bsum[tid] : 0;
  s[tid] = v;
  __syncthreads();
  for (int off = 1; off < 512; off <<= 1) {
    int t = (tid >= off) ? s[tid - off] : 0;
    __syncthreads();
    s[tid] += t;
    __syncthreads();
  }
  if (tid < nb) bsum[tid] = s[tid] - v;  // exclusive block offsets
}

__global__ void scan3_kernel(int* __restrict__ rowptr, const int* __restrict__ bsum,
                             int n, int E) {
  int i = blockIdx.x * 256 + threadIdx.x;
  if (i < n) rowptr[i] += bsum[blockIdx.x];
  if (i == 0) rowptr[n] = E;
}

__global__ void fill_kernel(const int* __restrict__ src, const int* __restrict__ dst,
                            const int* __restrict__ rowptr, int* __restrict__ rowctr,
                            int* __restrict__ col, int E) {
  int e = blockIdx.x * blockDim.x + threadIdx.x;
  if (e >= E) return;
  int d = dst[e];
  int pos = rowptr[d] + atomicAdd(&rowctr[d], 1);
  col[pos] = src[e];
}

// ---------------- neighbor mean (pull, wave-per-node) ----------------

__global__ void agg_kernel(const float* __restrict__ h, const int* __restrict__ rowptr,
                           const int* __restrict__ col, float* __restrict__ hm, int n) {
  int node = (blockIdx.x * blockDim.x + threadIdx.x) >> 6;
  int lane = threadIdx.x & 63;
  if (node >= n) return;
  int beg = rowptr[node];
  int end = rowptr[node + 1];
  float s0 = 0.f, s1 = 0.f, s2 = 0.f, s3 = 0.f;
  for (int base = beg; base < end; base += 64) {
    int cnt = min(64, end - base);
    int cidx = (base + lane < end) ? col[base + lane] : 0;
    int j = 0;
    for (; j + 3 < cnt; j += 4) {
      int i0 = __shfl(cidx, j + 0);
      int i1 = __shfl(cidx, j + 1);
      int i2 = __shfl(cidx, j + 2);
      int i3 = __shfl(cidx, j + 3);
      s0 += h[i0 * 64 + lane];
      s1 += h[i1 * 64 + lane];
      s2 += h[i2 * 64 + lane];
      s3 += h[i3 * 64 + lane];
    }
    for (; j < cnt; ++j) {
      s0 += h[__shfl(cidx, j) * 64 + lane];
    }
  }
  int d = end - beg;
  float inv = 1.0f / (float)(d > 0 ? d : 1);
  hm[node * 64 + lane] = (s0 + s1 + s2 + s3) * inv;
}

// ---------------- fused dual matvec + bias + BN partial stats ----------------
// z[r][f] = b[f] + sum_k Wself[f][k]*h[r][k] + Wneigh[f][k]*hm[r][k]
// lane = f, W rows held in registers (two halves), h/hm tiles in LDS (broadcast reads)

__global__ __launch_bounds__(256) void gemm_kernel(
    const float* __restrict__ h, const float* __restrict__ hm,
    const float* __restrict__ Wself, const float* __restrict__ Wneigh,
    const float* __restrict__ bias, float* __restrict__ z,
    float* __restrict__ stats, int n) {
  __shared__ float hs[64][64];
  __shared__ float hn[64][64];
  __shared__ float sred[128];
  int tid = threadIdx.x;
  int lane = tid & 63;
  int wid = tid >> 6;  // 0..3, wave handles rows wid*16..+15
  int rowbase = blockIdx.x * 64;

  // stage 64x64 tiles of h and hm (coalesced float4)
  #pragma unroll
  for (int it = 0; it < 4; ++it) {
    int idx = tid + it * 256;
    int r = idx >> 4;
    int c = idx & 15;
    int gr = rowbase + r;
    float4 v = make_float4(0.f, 0.f, 0.f, 0.f);
    float4 w = make_float4(0.f, 0.f, 0.f, 0.f);
    if (gr < n) {
      v = reinterpret_cast<const float4*>(h + (size_t)gr * 64)[c];
      w = reinterpret_cast<const float4*>(hm + (size_t)gr * 64)[c];
    }
    reinterpret_cast<float4*>(&hs[r][0])[c] = v;
    reinterpret_cast<float4*>(&hn[r][0])[c] = w;
  }
  if (tid < 128) sred[tid] = 0.f;
  __syncthreads();

  float acc[16];
  #pragma unroll
  for (int r = 0; r < 16; ++r) acc[r] = 0.f;

  const float4* wsp = reinterpret_cast<const float4*>(Wself + lane * 64);
  const float4* wnp = reinterpret_cast<const float4*>(Wneigh + lane * 64);

  #pragma unroll 1
  for (int half = 0; half < 2; ++half) {
    float4 ws[8], wn[8];
    #pragma unroll
    for (int kc = 0; kc < 8; ++kc) {
      ws[kc] = wsp[half * 8 + kc];
      wn[kc] = wnp[half * 8 + kc];
    }
    #pragma unroll
    for (int kc = 0; kc < 8; ++kc) {
      #pragma unroll
      for (int r = 0; r < 16; ++r) {
        int rr = wid * 16 + r;
        float4 a = reinterpret_cast<const float4*>(&hs[rr][0])[half * 8 + kc];
        float4 b = reinterpret_cast<const float4*>(&hn[rr][0])[half * 8 + kc];
        acc[r] += ws[kc].x * a.x + ws[kc].y * a.y + ws[kc].z * a.z + ws[kc].w * a.w
                + wn[kc].x * b.x + wn[kc].y * b.y + wn[kc].z * b.z + wn[kc].w * b.w;
      }
    }
  }

  float bv = bias[lane];
  float p1 = 0.f, p2 = 0.f;
  #pragma unroll
  for (int r = 0; r < 16; ++r) {
    int gr = rowbase + wid * 16 + r;
    if (gr < n) {
      float v = acc[r] + bv;
      z[(size_t)gr * 64 + lane] = v;
      p1 += v;
      p2 += v * v;
    }
  }
  atomicAdd(&sred[lane], p1);
  atomicAdd(&sred[64 + lane], p2);
  __syncthreads();
  if (tid < 128) atomicAdd(&stats[tid], sred[tid]);
}

// ---------------- BN (affine) + leaky relu ----------------

__global__ void bn_kernel(const float* z, const float* stats,
                          const float* gamma, const float* beta,
                          float* out, int n) {
  __shared__ float sc[64];
  __shared__ float sh[64];
  if (threadIdx.x < 64) {
    int f = threadIdx.x;
    float invN = 1.0f / (float)n;
    float mu = stats[f] * invN;
    float var = stats[64 + f] * invN - mu * mu;
    float s = rsqrtf(var + EPS) * gamma[f];
    sc[f] = s;
    sh[f] = beta[f] - mu * s;
  }
  __syncthreads();
  int total = n * 16;  // float4 count
  int stride = gridDim.x * blockDim.x;
  for (int idx = blockIdx.x * blockDim.x + threadIdx.x; idx < total; idx += stride) {
    int f0 = (idx & 15) * 4;
    float4 v = reinterpret_cast<const float4*>(z)[idx];
    float4 o;
    float t;
    t = v.x * sc[f0 + 0] + sh[f0 + 0]; o.x = t > 0.f ? t : SLOPE * t;
    t = v.y * sc[f0 + 1] + sh[f0 + 1]; o.y = t > 0.f ? t : SLOPE * t;
    t = v.z * sc[f0 + 2] + sh[f0 + 2]; o.z = t > 0.f ? t : SLOPE * t;
    t = v.w * sc[f0 + 3] + sh[f0 + 3]; o.w = t > 0.f ? t : SLOPE * t;
    reinterpret_cast<float4*>(out)[idx] = o;
  }
}

// ---------------- launch ----------------

extern "C" void kernel_launch(void* const* d_in, const int* in_sizes, int n_in,
                              void* d_out, int out_size, void* d_ws, size_t ws_size,
                              hipStream_t stream) {
  const float* x  = (const float*)d_in[0];
  const int* ei   = (const int*)d_in[1];
  const float* Ws1 = (const float*)d_in[2];
  const float* Wn1 = (const float*)d_in[3];
  const float* b1  = (const float*)d_in[4];
  const float* g1  = (const float*)d_in[5];
  const float* be1 = (const float*)d_in[6];
  const float* Ws2 = (const float*)d_in[7];
  const float* Wn2 = (const float*)d_in[8];
  const float* b2  = (const float*)d_in[9];
  const float* g2  = (const float*)d_in[10];
  const float* be2 = (const float*)d_in[11];
  float* out = (float*)d_out;

  int N = in_sizes[0] / 64;
  int E = in_sizes[1] / 2;
  const int* src = ei;
  const int* dst = ei + E;

  // workspace layout
  char* ws = (char*)d_ws;
  int* deg = (int*)ws;                       // N
  int* rowctr = deg + N;                     // N
  float* stats1 = (float*)(rowctr + N);      // 128
  float* stats2 = stats1 + 128;              // 128
  size_t zbytes = (size_t)N * 8 + 1024;      // deg + rowctr + stats
  size_t off = (zbytes + 255) & ~(size_t)255;
  auto take = [&](size_t bytes) {
    void* p = ws + off;
    off = (off + bytes + 255) & ~(size_t)255;
    return p;
  };
  int* rowptr = (int*)take((size_t)(N + 1) * 4);
  int* bsum   = (int*)take(512 * 4);
  int* col    = (int*)take((size_t)E * 4);
  float* hm   = (float*)take((size_t)N * 64 * 4);
  float* h1   = (float*)take((size_t)N * 64 * 4);

  hipMemsetAsync(ws, 0, zbytes, stream);

  int eb = (E + 255) / 256;
  int nb = (N + 255) / 256;
  deg_kernel<<<eb, 256, 0, stream>>>(dst, deg, E);
  scan1_kernel<<<nb, 256, 0, stream>>>(deg, rowptr, bsum, N);
  scan2_kernel<<<1, 512, 0, stream>>>(bsum, nb);
  scan3_kernel<<<nb, 256, 0, stream>>>(rowptr, bsum, N, E);
  fill_kernel<<<eb, 256, 0, stream>>>(src, dst, rowptr, rowctr, col, E);

  int ab = (N + 3) / 4;      // 4 waves (nodes) per block
  int gb = (N + 63) / 64;    // 64 rows per block

  // layer 1
  agg_kernel<<<ab, 256, 0, stream>>>(x, rowptr, col, hm, N);
  gemm_kernel<<<gb, 256, 0, stream>>>(x, hm, Ws1, Wn1, b1, out, stats1, N);
  bn_kernel<<<2048, 256, 0, stream>>>(out, stats1, g1, be1, h1, N);

  // layer 2
  agg_kernel<<<ab, 256, 0, stream>>>(h1, rowptr, col, hm, N);
  gemm_kernel<<<gb, 256, 0, stream>>>(h1, hm, Ws2, Wn2, b2, out, stats2, N);
  bn_kernel<<<2048, 256, 0, stream>>>(out, stats2, g2, be2, out, N);
}

// Round 2
// 411.856 us; speedup vs baseline: 1.4021x; 1.4021x over previous
//
#include <hip/hip_runtime.h>

#define EPS 1e-5f
#define SLOPE 0.01f

typedef short bf16x8 __attribute__((ext_vector_type(8)));
typedef float f32x4 __attribute__((ext_vector_type(4)));

static __device__ __forceinline__ unsigned short f2bf(float f) {
  unsigned u = __float_as_uint(f);
  unsigned r = (u + 0x7FFFu + ((u >> 16) & 1u)) >> 16;
  return (unsigned short)r;
}
static __device__ __forceinline__ float bf2f(unsigned short h) {
  return __uint_as_float(((unsigned)h) << 16);
}

// ---------------- CSR build ----------------

__global__ void deg_kernel(const int* __restrict__ dst, int* __restrict__ deg, int E) {
  int e = blockIdx.x * blockDim.x + threadIdx.x;
  if (e < E) atomicAdd(&deg[dst[e]], 1);
}

__global__ void scan1_kernel(const int* __restrict__ deg, int* __restrict__ rowptr,
                             int* __restrict__ bsum, int n) {
  __shared__ int s[256];
  int i = blockIdx.x * 256 + threadIdx.x;
  int v = (i < n) ? deg[i] : 0;
  s[threadIdx.x] = v;
  __syncthreads();
  for (int off = 1; off < 256; off <<= 1) {
    int t = (threadIdx.x >= off) ? s[threadIdx.x - off] : 0;
    __syncthreads();
    s[threadIdx.x] += t;
    __syncthreads();
  }
  if (i < n) rowptr[i] = s[threadIdx.x] - v;  // exclusive within block
  if (threadIdx.x == 255) bsum[blockIdx.x] = s[255];
}

__global__ void scan2_kernel(int* __restrict__ bsum, int nb) {
  __shared__ int s[512];
  int tid = threadIdx.x;
  int v = (tid < nb) ? bsum[tid] : 0;
  s[tid] = v;
  __syncthreads();
  for (int off = 1; off < 512; off <<= 1) {
    int t = (tid >= off) ? s[tid - off] : 0;
    __syncthreads();
    s[tid] += t;
    __syncthreads();
  }
  if (tid < nb) bsum[tid] = s[tid] - v;  // exclusive block offsets
}

__global__ void scan3_kernel(int* __restrict__ rowptr, const int* __restrict__ bsum,
                             int n, int E) {
  int i = blockIdx.x * 256 + threadIdx.x;
  if (i < n) rowptr[i] += bsum[blockIdx.x];
  if (i == 0) rowptr[n] = E;
}

__global__ void fill_kernel(const int* __restrict__ src, const int* __restrict__ dst,
                            const int* __restrict__ rowptr, int* __restrict__ rowctr,
                            int* __restrict__ col, int E) {
  int e = blockIdx.x * blockDim.x + threadIdx.x;
  if (e >= E) return;
  int d = dst[e];
  int pos = rowptr[d] + atomicAdd(&rowctr[d], 1);
  col[pos] = src[e];
}

// ---------------- f32 -> bf16 conversion ----------------

__global__ void cvt_kernel(const float* __restrict__ x, unsigned short* __restrict__ xb,
                           int total4) {  // total4 = total/4
  int stride = gridDim.x * blockDim.x;
  for (int i = blockIdx.x * blockDim.x + threadIdx.x; i < total4; i += stride) {
    float4 v = reinterpret_cast<const float4*>(x)[i];
    ushort4 o;
    o.x = f2bf(v.x); o.y = f2bf(v.y); o.z = f2bf(v.z); o.w = f2bf(v.w);
    reinterpret_cast<ushort4*>(xb)[i] = o;
  }
}

// ---------------- neighbor mean (pull, wave-per-node, bf16) ----------------

__global__ void agg_kernel(const unsigned short* __restrict__ hb,
                           const int* __restrict__ rowptr,
                           const int* __restrict__ col,
                           unsigned short* __restrict__ hm, int n) {
  int node = (blockIdx.x * blockDim.x + threadIdx.x) >> 6;
  int lane = threadIdx.x & 63;
  if (node >= n) return;
  int beg = rowptr[node];
  int end = rowptr[node + 1];
  float s0 = 0.f, s1 = 0.f, s2 = 0.f, s3 = 0.f;
  for (int base = beg; base < end; base += 64) {
    int cnt = min(64, end - base);
    int cidx = (base + lane < end) ? col[base + lane] : 0;
    int j = 0;
    for (; j + 3 < cnt; j += 4) {
      int i0 = __shfl(cidx, j + 0);
      int i1 = __shfl(cidx, j + 1);
      int i2 = __shfl(cidx, j + 2);
      int i3 = __shfl(cidx, j + 3);
      s0 += bf2f(hb[(size_t)i0 * 64 + lane]);
      s1 += bf2f(hb[(size_t)i1 * 64 + lane]);
      s2 += bf2f(hb[(size_t)i2 * 64 + lane]);
      s3 += bf2f(hb[(size_t)i3 * 64 + lane]);
    }
    for (; j < cnt; ++j) {
      s0 += bf2f(hb[(size_t)__shfl(cidx, j) * 64 + lane]);
    }
  }
  int d = end - beg;
  float inv = 1.0f / (float)(d > 0 ? d : 1);
  hm[(size_t)node * 64 + lane] = f2bf((s0 + s1 + s2 + s3) * inv);
}

// ---------------- MFMA GEMM: z = [A0|A1] @ [Wself|Wneigh]^T + b, + BN stats ----------------
// 64 rows x 64 f per block, K=128 (concat). 4 waves, wave w = rows 16w..16w+15.

#define LDK 136  // row stride in bf16 elements (128 + 8 pad -> 272 B, conflict-free)

__global__ __launch_bounds__(256) void gemm_mfma(
    const unsigned short* __restrict__ A0,   // [n][64] bf16 (self)
    const unsigned short* __restrict__ A1,   // [n][64] bf16 (neigh mean)
    const float* __restrict__ Wself, const float* __restrict__ Wneigh,  // [64][64] f32
    const float* __restrict__ bias,
    float* __restrict__ z, float* __restrict__ stats, int n) {
  __shared__ unsigned short X[64 * LDK];
  __shared__ unsigned short W[64 * LDK];
  __shared__ float sred[128];
  int tid = threadIdx.x;
  int rowbase = blockIdx.x * 64;

  // stage X (rows of [A0|A1]) and W (rows of [Wself|Wneigh], f32->bf16)
  #pragma unroll
  for (int it = 0; it < 4; ++it) {
    int c = tid + it * 256;        // 0..1023 chunks of 8 elements
    int r = c >> 4;                // 0..63
    int half = (c >> 3) & 1;
    int off = (c & 7) * 8;         // 0,8,..,56
    int gr = rowbase + r;
    uint4 v = make_uint4(0u, 0u, 0u, 0u);
    if (gr < n) {
      const unsigned short* srcp = (half ? A1 : A0) + (size_t)gr * 64 + off;
      v = *reinterpret_cast<const uint4*>(srcp);
    }
    *reinterpret_cast<uint4*>(&X[r * LDK + half * 64 + off]) = v;

    const float* wp = (half ? Wneigh : Wself) + r * 64 + off;
    float4 w0 = *reinterpret_cast<const float4*>(wp);
    float4 w1 = *reinterpret_cast<const float4*>(wp + 4);
    ushort4 wa, wb;
    wa.x = f2bf(w0.x); wa.y = f2bf(w0.y); wa.z = f2bf(w0.z); wa.w = f2bf(w0.w);
    wb.x = f2bf(w1.x); wb.y = f2bf(w1.y); wb.z = f2bf(w1.z); wb.w = f2bf(w1.w);
    unsigned short* wd = &W[r * LDK + half * 64 + off];
    *reinterpret_cast<ushort4*>(wd) = wa;
    *reinterpret_cast<ushort4*>(wd + 4) = wb;
  }
  if (tid < 128) sred[tid] = 0.f;
  __syncthreads();

  int lane = tid & 63;
  int w = tid >> 6;
  int l15 = lane & 15;
  int g = lane >> 4;

  f32x4 acc[4] = {};  // one 16x16 tile per f-tile t
  #pragma unroll
  for (int s = 0; s < 4; ++s) {  // k-steps of 32
    bf16x8 a = *reinterpret_cast<const bf16x8*>(&X[(w * 16 + l15) * LDK + s * 32 + g * 8]);
    #pragma unroll
    for (int t = 0; t < 4; ++t) {
      bf16x8 b = *reinterpret_cast<const bf16x8*>(&W[(t * 16 + l15) * LDK + s * 32 + g * 8]);
      acc[t] = __builtin_amdgcn_mfma_f32_16x16x32_bf16(a, b, acc[t], 0, 0, 0);
    }
  }

  // epilogue: bias, z store (f32), BN partial stats
  #pragma unroll
  for (int t = 0; t < 4; ++t) {
    int f = t * 16 + l15;
    float bb = bias[f];
    float p1 = 0.f, p2 = 0.f;
    #pragma unroll
    for (int i = 0; i < 4; ++i) {
      int gr = rowbase + w * 16 + g * 4 + i;
      if (gr < n) {
        float v = acc[t][i] + bb;
        z[(size_t)gr * 64 + f] = v;
        p1 += v;
        p2 += v * v;
      }
    }
    atomicAdd(&sred[f], p1);
    atomicAdd(&sred[64 + f], p2);
  }
  __syncthreads();
  if (tid < 128) atomicAdd(&stats[tid], sred[tid]);
}

// ---------------- BN (affine) + leaky relu ----------------

__global__ void bn_bf16_kernel(const float* __restrict__ z, const float* __restrict__ stats,
                               const float* __restrict__ gamma, const float* __restrict__ beta,
                               unsigned short* __restrict__ out, int n) {
  __shared__ float sc[64];
  __shared__ float sh[64];
  if (threadIdx.x < 64) {
    int f = threadIdx.x;
    float invN = 1.0f / (float)n;
    float mu = stats[f] * invN;
    float var = stats[64 + f] * invN - mu * mu;
    float s = rsqrtf(var + EPS) * gamma[f];
    sc[f] = s;
    sh[f] = beta[f] - mu * s;
  }
  __syncthreads();
  int total = n * 16;  // float4 chunks
  int stride = gridDim.x * blockDim.x;
  for (int idx = blockIdx.x * blockDim.x + threadIdx.x; idx < total; idx += stride) {
    int f0 = (idx & 15) * 4;
    float4 v = reinterpret_cast<const float4*>(z)[idx];
    float t;
    ushort4 o;
    t = v.x * sc[f0 + 0] + sh[f0 + 0]; o.x = f2bf(t > 0.f ? t : SLOPE * t);
    t = v.y * sc[f0 + 1] + sh[f0 + 1]; o.y = f2bf(t > 0.f ? t : SLOPE * t);
    t = v.z * sc[f0 + 2] + sh[f0 + 2]; o.z = f2bf(t > 0.f ? t : SLOPE * t);
    t = v.w * sc[f0 + 3] + sh[f0 + 3]; o.w = f2bf(t > 0.f ? t : SLOPE * t);
    reinterpret_cast<ushort4*>(out)[idx] = o;
  }
}

__global__ void bn_f32_kernel(const float* __restrict__ z, const float* __restrict__ stats,
                              const float* __restrict__ gamma, const float* __restrict__ beta,
                              float* __restrict__ out, int n) {
  __shared__ float sc[64];
  __shared__ float sh[64];
  if (threadIdx.x < 64) {
    int f = threadIdx.x;
    float invN = 1.0f / (float)n;
    float mu = stats[f] * invN;
    float var = stats[64 + f] * invN - mu * mu;
    float s = rsqrtf(var + EPS) * gamma[f];
    sc[f] = s;
    sh[f] = beta[f] - mu * s;
  }
  __syncthreads();
  int total = n * 16;
  int stride = gridDim.x * blockDim.x;
  for (int idx = blockIdx.x * blockDim.x + threadIdx.x; idx < total; idx += stride) {
    int f0 = (idx & 15) * 4;
    float4 v = reinterpret_cast<const float4*>(z)[idx];
    float4 o;
    float t;
    t = v.x * sc[f0 + 0] + sh[f0 + 0]; o.x = t > 0.f ? t : SLOPE * t;
    t = v.y * sc[f0 + 1] + sh[f0 + 1]; o.y = t > 0.f ? t : SLOPE * t;
    t = v.z * sc[f0 + 2] + sh[f0 + 2]; o.z = t > 0.f ? t : SLOPE * t;
    t = v.w * sc[f0 + 3] + sh[f0 + 3]; o.w = t > 0.f ? t : SLOPE * t;
    reinterpret_cast<float4*>(out)[idx] = o;
  }
}

// ---------------- launch ----------------

extern "C" void kernel_launch(void* const* d_in, const int* in_sizes, int n_in,
                              void* d_out, int out_size, void* d_ws, size_t ws_size,
                              hipStream_t stream) {
  const float* x  = (const float*)d_in[0];
  const int* ei   = (const int*)d_in[1];
  const float* Ws1 = (const float*)d_in[2];
  const float* Wn1 = (const float*)d_in[3];
  const float* b1  = (const float*)d_in[4];
  const float* g1  = (const float*)d_in[5];
  const float* be1 = (const float*)d_in[6];
  const float* Ws2 = (const float*)d_in[7];
  const float* Wn2 = (const float*)d_in[8];
  const float* b2  = (const float*)d_in[9];
  const float* g2  = (const float*)d_in[10];
  const float* be2 = (const float*)d_in[11];
  float* out = (float*)d_out;

  int N = in_sizes[0] / 64;
  int E = in_sizes[1] / 2;
  const int* src = ei;
  const int* dst = ei + E;

  // workspace layout
  char* ws = (char*)d_ws;
  int* deg = (int*)ws;                       // N
  int* rowctr = deg + N;                     // N
  float* stats1 = (float*)(rowctr + N);      // 128
  float* stats2 = stats1 + 128;              // 128
  size_t zbytes = (size_t)N * 8 + 1024;      // deg + rowctr + stats (zeroed each call)
  size_t off = (zbytes + 255) & ~(size_t)255;
  auto take = [&](size_t bytes) {
    void* p = ws + off;
    off = (off + bytes + 255) & ~(size_t)255;
    return p;
  };
  int* rowptr = (int*)take((size_t)(N + 1) * 4);
  int* bsum   = (int*)take(512 * 4);
  int* col    = (int*)take((size_t)E * 4);
  unsigned short* xb  = (unsigned short*)take((size_t)N * 64 * 2);
  unsigned short* hmb = (unsigned short*)take((size_t)N * 64 * 2);
  unsigned short* h1b = (unsigned short*)take((size_t)N * 64 * 2);

  hipMemsetAsync(ws, 0, zbytes, stream);

  int eb = (E + 255) / 256;
  int nb = (N + 255) / 256;
  deg_kernel<<<eb, 256, 0, stream>>>(dst, deg, E);
  scan1_kernel<<<nb, 256, 0, stream>>>(deg, rowptr, bsum, N);
  scan2_kernel<<<1, 512, 0, stream>>>(bsum, nb);
  scan3_kernel<<<nb, 256, 0, stream>>>(rowptr, bsum, N, E);
  fill_kernel<<<eb, 256, 0, stream>>>(src, dst, rowptr, rowctr, col, E);

  cvt_kernel<<<1024, 256, 0, stream>>>(x, xb, N * 16);

  int ab = (N + 3) / 4;      // 4 wave-nodes per block
  int gb = (N + 63) / 64;    // 64 rows per block

  // layer 1 (z staged in d_out)
  agg_kernel<<<ab, 256, 0, stream>>>(xb, rowptr, col, hmb, N);
  gemm_mfma<<<gb, 256, 0, stream>>>(xb, hmb, Ws1, Wn1, b1, out, stats1, N);
  bn_bf16_kernel<<<2048, 256, 0, stream>>>(out, stats1, g1, be1, h1b, N);

  // layer 2
  agg_kernel<<<ab, 256, 0, stream>>>(h1b, rowptr, col, hmb, N);
  gemm_mfma<<<gb, 256, 0, stream>>>(h1b, hmb, Ws2, Wn2, b2, out, stats2, N);
  bn_f32_kernel<<<2048, 256, 0, stream>>>(out, stats2, g2, be2, out, N);
}

// Round 3
// 373.672 us; speedup vs baseline: 1.5453x; 1.1022x over previous
//
#include <hip/hip_runtime.h>

#define EPS 1e-5f
#define SLOPE 0.01f

typedef short bf16x8 __attribute__((ext_vector_type(8)));
typedef float f32x4 __attribute__((ext_vector_type(4)));

static __device__ __forceinline__ unsigned short f2bf(float f) {
  unsigned u = __float_as_uint(f);
  unsigned r = (u + 0x7FFFu + ((u >> 16) & 1u)) >> 16;
  return (unsigned short)r;
}
static __device__ __forceinline__ float bf2f(unsigned short h) {
  return __uint_as_float(((unsigned)h) << 16);
}

// ---------------- CSR build (XCD-partitioned by dst range) ----------------
// blockIdx.x & 7 -> XCD (round-robin heuristic). Each range r owns nodes
// [r*STEP, (r+1)*STEP): its deg/rowctr atomics and col writes stay in one
// XCD's L2 -> no cross-XCD line bouncing, ~1x write amplification.

__global__ void deg_kernel(const int* __restrict__ dst, int* __restrict__ deg,
                           int E, int step) {
  int r = blockIdx.x & 7;
  int ch = blockIdx.x >> 3;
  int nch = gridDim.x >> 3;
  int lo = r * step, hi = lo + step;
  int E4 = E >> 2;
  int span = (E4 + nch - 1) / nch;
  int s = ch * span, e = min(E4, s + span);
  const int4* d4p = (const int4*)dst;
  for (int i = s + threadIdx.x; i < e; i += blockDim.x) {
    int4 d = d4p[i];
    if (d.x >= lo && d.x < hi) atomicAdd(&deg[d.x], 1);
    if (d.y >= lo && d.y < hi) atomicAdd(&deg[d.y], 1);
    if (d.z >= lo && d.z < hi) atomicAdd(&deg[d.z], 1);
    if (d.w >= lo && d.w < hi) atomicAdd(&deg[d.w], 1);
  }
  if (ch == 0) {
    for (int i = (E4 << 2) + threadIdx.x; i < E; i += blockDim.x) {
      int d = dst[i];
      if (d >= lo && d < hi) atomicAdd(&deg[d], 1);
    }
  }
}

__global__ void scan1_kernel(const int* __restrict__ deg, int* __restrict__ rowptr,
                             int* __restrict__ bsum, int n) {
  __shared__ int s[256];
  int i = blockIdx.x * 256 + threadIdx.x;
  int v = (i < n) ? deg[i] : 0;
  s[threadIdx.x] = v;
  __syncthreads();
  for (int off = 1; off < 256; off <<= 1) {
    int t = (threadIdx.x >= off) ? s[threadIdx.x - off] : 0;
    __syncthreads();
    s[threadIdx.x] += t;
    __syncthreads();
  }
  if (i < n) rowptr[i] = s[threadIdx.x] - v;  // exclusive within block
  if (threadIdx.x == 255) bsum[blockIdx.x] = s[255];
}

__global__ void scan2_kernel(int* __restrict__ bsum, int nb) {
  __shared__ int s[512];
  int tid = threadIdx.x;
  int v = (tid < nb) ? bsum[tid] : 0;
  s[tid] = v;
  __syncthreads();
  for (int off = 1; off < 512; off <<= 1) {
    int t = (tid >= off) ? s[tid - off] : 0;
    __syncthreads();
    s[tid] += t;
    __syncthreads();
  }
  if (tid < nb) bsum[tid] = s[tid] - v;  // exclusive block offsets
}

__global__ void scan3_kernel(int* __restrict__ rowptr, const int* __restrict__ bsum,
                             int n, int E) {
  int i = blockIdx.x * 256 + threadIdx.x;
  if (i < n) rowptr[i] += bsum[blockIdx.x];
  if (i == 0) rowptr[n] = E;
}

__global__ void fill_kernel(const int* __restrict__ src, const int* __restrict__ dst,
                            const int* __restrict__ rowptr, int* __restrict__ rowctr,
                            int* __restrict__ col, int E, int step) {
  int r = blockIdx.x & 7;
  int ch = blockIdx.x >> 3;
  int nch = gridDim.x >> 3;
  int lo = r * step, hi = lo + step;
  int E4 = E >> 2;
  int span = (E4 + nch - 1) / nch;
  int s = ch * span, e = min(E4, s + span);
  const int4* d4p = (const int4*)dst;
  const int4* s4p = (const int4*)src;
  for (int i = s + threadIdx.x; i < e; i += blockDim.x) {
    int4 d = d4p[i];
    int4 sv = s4p[i];
    if (d.x >= lo && d.x < hi) col[rowptr[d.x] + atomicAdd(&rowctr[d.x], 1)] = sv.x;
    if (d.y >= lo && d.y < hi) col[rowptr[d.y] + atomicAdd(&rowctr[d.y], 1)] = sv.y;
    if (d.z >= lo && d.z < hi) col[rowptr[d.z] + atomicAdd(&rowctr[d.z], 1)] = sv.z;
    if (d.w >= lo && d.w < hi) col[rowptr[d.w] + atomicAdd(&rowctr[d.w], 1)] = sv.w;
  }
  if (ch == 0) {
    for (int i = (E4 << 2) + threadIdx.x; i < E; i += blockDim.x) {
      int d = dst[i];
      if (d >= lo && d < hi) col[rowptr[d] + atomicAdd(&rowctr[d], 1)] = src[i];
    }
  }
}

// ---------------- f32 -> bf16 conversion ----------------

__global__ void cvt_kernel(const float* __restrict__ x, unsigned short* __restrict__ xb,
                           int total4) {
  int stride = gridDim.x * blockDim.x;
  for (int i = blockIdx.x * blockDim.x + threadIdx.x; i < total4; i += stride) {
    float4 v = reinterpret_cast<const float4*>(x)[i];
    ushort4 o;
    o.x = f2bf(v.x); o.y = f2bf(v.y); o.z = f2bf(v.z); o.w = f2bf(v.w);
    reinterpret_cast<ushort4*>(xb)[i] = o;
  }
}

// ---------------- neighbor mean (pull, wave-per-node, 4 rows/instr) ----------------
// lane = quarter qr (row j+qr) x 4-feature slice fo. 8B uint2 gather per lane
// -> 512B per wave instruction. bf16 unpack via shift/mask (hi half of a bf16
// pair is already a valid f32). Quarter-wave shfl_xor reduce at the end.

__global__ void agg_kernel(const unsigned short* __restrict__ hb,
                           const int* __restrict__ rowptr,
                           const int* __restrict__ col,
                           unsigned short* __restrict__ hm, int n) {
  int node = (blockIdx.x * blockDim.x + threadIdx.x) >> 6;
  int lane = threadIdx.x & 63;
  if (node >= n) return;
  int beg = rowptr[node];
  int end = rowptr[node + 1];
  int qr = lane >> 4;        // 0..3: which neighbor in the group of 4
  int fo = (lane & 15) * 4;  // feature offset: 4 feats per lane
  float s0 = 0.f, s1 = 0.f, s2 = 0.f, s3 = 0.f;
  for (int base = beg; base < end; base += 64) {
    int cnt = min(64, end - base);
    int cidx = (base + lane < end) ? col[base + lane] : 0;
    for (int j = 0; j < cnt; j += 4) {
      int jj = j + qr;
      int idx = __shfl(cidx, jj);
      if (jj < cnt) {
        uint2 u = *reinterpret_cast<const uint2*>(&hb[(size_t)idx * 64 + fo]);
        s0 += __uint_as_float(u.x << 16);
        s1 += __uint_as_float(u.x & 0xFFFF0000u);
        s2 += __uint_as_float(u.y << 16);
        s3 += __uint_as_float(u.y & 0xFFFF0000u);
      }
    }
  }
  s0 += __shfl_xor(s0, 16); s1 += __shfl_xor(s1, 16);
  s2 += __shfl_xor(s2, 16); s3 += __shfl_xor(s3, 16);
  s0 += __shfl_xor(s0, 32); s1 += __shfl_xor(s1, 32);
  s2 += __shfl_xor(s2, 32); s3 += __shfl_xor(s3, 32);
  if (lane < 16) {
    int d = end - beg;
    float inv = 1.0f / (float)(d > 0 ? d : 1);
    ushort4 o;
    o.x = f2bf(s0 * inv); o.y = f2bf(s1 * inv);
    o.z = f2bf(s2 * inv); o.w = f2bf(s3 * inv);
    *reinterpret_cast<ushort4*>(&hm[(size_t)node * 64 + fo]) = o;
  }
}

// ---------------- MFMA GEMM: z = [A0|A1] @ [Wself|Wneigh]^T + b, + BN stats ----------------

#define LDK 136  // row stride in bf16 elements (272 B, conflict-free b128)

__global__ __launch_bounds__(256) void gemm_mfma(
    const unsigned short* __restrict__ A0,
    const unsigned short* __restrict__ A1,
    const float* __restrict__ Wself, const float* __restrict__ Wneigh,
    const float* __restrict__ bias,
    float* __restrict__ z, float* __restrict__ stats, int n) {
  __shared__ unsigned short X[64 * LDK];
  __shared__ unsigned short W[64 * LDK];
  __shared__ float sred[128];
  int tid = threadIdx.x;
  int rowbase = blockIdx.x * 64;

  #pragma unroll
  for (int it = 0; it < 4; ++it) {
    int c = tid + it * 256;
    int r = c >> 4;
    int half = (c >> 3) & 1;
    int off = (c & 7) * 8;
    int gr = rowbase + r;
    uint4 v = make_uint4(0u, 0u, 0u, 0u);
    if (gr < n) {
      const unsigned short* srcp = (half ? A1 : A0) + (size_t)gr * 64 + off;
      v = *reinterpret_cast<const uint4*>(srcp);
    }
    *reinterpret_cast<uint4*>(&X[r * LDK + half * 64 + off]) = v;

    const float* wp = (half ? Wneigh : Wself) + r * 64 + off;
    float4 w0 = *reinterpret_cast<const float4*>(wp);
    float4 w1 = *reinterpret_cast<const float4*>(wp + 4);
    ushort4 wa, wb;
    wa.x = f2bf(w0.x); wa.y = f2bf(w0.y); wa.z = f2bf(w0.z); wa.w = f2bf(w0.w);
    wb.x = f2bf(w1.x); wb.y = f2bf(w1.y); wb.z = f2bf(w1.z); wb.w = f2bf(w1.w);
    unsigned short* wd = &W[r * LDK + half * 64 + off];
    *reinterpret_cast<ushort4*>(wd) = wa;
    *reinterpret_cast<ushort4*>(wd + 4) = wb;
  }
  if (tid < 128) sred[tid] = 0.f;
  __syncthreads();

  int lane = tid & 63;
  int w = tid >> 6;
  int l15 = lane & 15;
  int g = lane >> 4;

  f32x4 acc[4] = {};
  #pragma unroll
  for (int s = 0; s < 4; ++s) {
    bf16x8 a = *reinterpret_cast<const bf16x8*>(&X[(w * 16 + l15) * LDK + s * 32 + g * 8]);
    #pragma unroll
    for (int t = 0; t < 4; ++t) {
      bf16x8 b = *reinterpret_cast<const bf16x8*>(&W[(t * 16 + l15) * LDK + s * 32 + g * 8]);
      acc[t] = __builtin_amdgcn_mfma_f32_16x16x32_bf16(a, b, acc[t], 0, 0, 0);
    }
  }

  #pragma unroll
  for (int t = 0; t < 4; ++t) {
    int f = t * 16 + l15;
    float bb = bias[f];
    float p1 = 0.f, p2 = 0.f;
    #pragma unroll
    for (int i = 0; i < 4; ++i) {
      int gr = rowbase + w * 16 + g * 4 + i;
      if (gr < n) {
        float v = acc[t][i] + bb;
        z[(size_t)gr * 64 + f] = v;
        p1 += v;
        p2 += v * v;
      }
    }
    atomicAdd(&sred[f], p1);
    atomicAdd(&sred[64 + f], p2);
  }
  __syncthreads();
  if (tid < 128) atomicAdd(&stats[tid], sred[tid]);
}

// ---------------- BN (affine) + leaky relu ----------------

__global__ void bn_bf16_kernel(const float* __restrict__ z, const float* __restrict__ stats,
                               const float* __restrict__ gamma, const float* __restrict__ beta,
                               unsigned short* __restrict__ out, int n) {
  __shared__ float sc[64];
  __shared__ float sh[64];
  if (threadIdx.x < 64) {
    int f = threadIdx.x;
    float invN = 1.0f / (float)n;
    float mu = stats[f] * invN;
    float var = stats[64 + f] * invN - mu * mu;
    float s = rsqrtf(var + EPS) * gamma[f];
    sc[f] = s;
    sh[f] = beta[f] - mu * s;
  }
  __syncthreads();
  int total = n * 16;
  int stride = gridDim.x * blockDim.x;
  for (int idx = blockIdx.x * blockDim.x + threadIdx.x; idx < total; idx += stride) {
    int f0 = (idx & 15) * 4;
    float4 v = reinterpret_cast<const float4*>(z)[idx];
    float t;
    ushort4 o;
    t = v.x * sc[f0 + 0] + sh[f0 + 0]; o.x = f2bf(t > 0.f ? t : SLOPE * t);
    t = v.y * sc[f0 + 1] + sh[f0 + 1]; o.y = f2bf(t > 0.f ? t : SLOPE * t);
    t = v.z * sc[f0 + 2] + sh[f0 + 2]; o.z = f2bf(t > 0.f ? t : SLOPE * t);
    t = v.w * sc[f0 + 3] + sh[f0 + 3]; o.w = f2bf(t > 0.f ? t : SLOPE * t);
    reinterpret_cast<ushort4*>(out)[idx] = o;
  }
}

__global__ void bn_f32_kernel(const float* __restrict__ z, const float* __restrict__ stats,
                              const float* __restrict__ gamma, const float* __restrict__ beta,
                              float* __restrict__ out, int n) {
  __shared__ float sc[64];
  __shared__ float sh[64];
  if (threadIdx.x < 64) {
    int f = threadIdx.x;
    float invN = 1.0f / (float)n;
    float mu = stats[f] * invN;
    float var = stats[64 + f] * invN - mu * mu;
    float s = rsqrtf(var + EPS) * gamma[f];
    sc[f] = s;
    sh[f] = beta[f] - mu * s;
  }
  __syncthreads();
  int total = n * 16;
  int stride = gridDim.x * blockDim.x;
  for (int idx = blockIdx.x * blockDim.x + threadIdx.x; idx < total; idx += stride) {
    int f0 = (idx & 15) * 4;
    float4 v = reinterpret_cast<const float4*>(z)[idx];
    float4 o;
    float t;
    t = v.x * sc[f0 + 0] + sh[f0 + 0]; o.x = t > 0.f ? t : SLOPE * t;
    t = v.y * sc[f0 + 1] + sh[f0 + 1]; o.y = t > 0.f ? t : SLOPE * t;
    t = v.z * sc[f0 + 2] + sh[f0 + 2]; o.z = t > 0.f ? t : SLOPE * t;
    t = v.w * sc[f0 + 3] + sh[f0 + 3]; o.w = t > 0.f ? t : SLOPE * t;
    reinterpret_cast<float4*>(out)[idx] = o;
  }
}

// ---------------- launch ----------------

extern "C" void kernel_launch(void* const* d_in, const int* in_sizes, int n_in,
                              void* d_out, int out_size, void* d_ws, size_t ws_size,
                              hipStream_t stream) {
  const float* x  = (const float*)d_in[0];
  const int* ei   = (const int*)d_in[1];
  const float* Ws1 = (const float*)d_in[2];
  const float* Wn1 = (const float*)d_in[3];
  const float* b1  = (const float*)d_in[4];
  const float* g1  = (const float*)d_in[5];
  const float* be1 = (const float*)d_in[6];
  const float* Ws2 = (const float*)d_in[7];
  const float* Wn2 = (const float*)d_in[8];
  const float* b2  = (const float*)d_in[9];
  const float* g2  = (const float*)d_in[10];
  const float* be2 = (const float*)d_in[11];
  float* out = (float*)d_out;

  int N = in_sizes[0] / 64;
  int E = in_sizes[1] / 2;
  const int* src = ei;
  const int* dst = ei + E;
  int step = (N + 7) / 8;  // nodes per XCD range

  char* ws = (char*)d_ws;
  int* deg = (int*)ws;                       // N
  int* rowctr = deg + N;                     // N
  float* stats1 = (float*)(rowctr + N);      // 128
  float* stats2 = stats1 + 128;              // 128
  size_t zbytes = (size_t)N * 8 + 1024;
  size_t off = (zbytes + 255) & ~(size_t)255;
  auto take = [&](size_t bytes) {
    void* p = ws + off;
    off = (off + bytes + 255) & ~(size_t)255;
    return p;
  };
  int* rowptr = (int*)take((size_t)(N + 1) * 4);
  int* bsum   = (int*)take(512 * 4);
  int* col    = (int*)take((size_t)E * 4);
  unsigned short* xb  = (unsigned short*)take((size_t)N * 64 * 2);
  unsigned short* hmb = (unsigned short*)take((size_t)N * 64 * 2);
  unsigned short* h1b = (unsigned short*)take((size_t)N * 64 * 2);

  hipMemsetAsync(ws, 0, zbytes, stream);

  int nb = (N + 255) / 256;
  int csr_grid = 8 * 128;  // 8 ranges x 128 chunks
  deg_kernel<<<csr_grid, 256, 0, stream>>>(dst, deg, E, step);
  scan1_kernel<<<nb, 256, 0, stream>>>(deg, rowptr, bsum, N);
  scan2_kernel<<<1, 512, 0, stream>>>(bsum, nb);
  scan3_kernel<<<nb, 256, 0, stream>>>(rowptr, bsum, N, E);
  fill_kernel<<<csr_grid, 256, 0, stream>>>(src, dst, rowptr, rowctr, col, E, step);

  cvt_kernel<<<1024, 256, 0, stream>>>(x, xb, N * 16);

  int ab = (N + 3) / 4;
  int gb = (N + 63) / 64;

  // layer 1 (z staged in d_out)
  agg_kernel<<<ab, 256, 0, stream>>>(xb, rowptr, col, hmb, N);
  gemm_mfma<<<gb, 256, 0, stream>>>(xb, hmb, Ws1, Wn1, b1, out, stats1, N);
  bn_bf16_kernel<<<2048, 256, 0, stream>>>(out, stats1, g1, be1, h1b, N);

  // layer 2
  agg_kernel<<<ab, 256, 0, stream>>>(h1b, rowptr, col, hmb, N);
  gemm_mfma<<<gb, 256, 0, stream>>>(h1b, hmb, Ws2, Wn2, b2, out, stats2, N);
  bn_f32_kernel<<<2048, 256, 0, stream>>>(out, stats2, g2, be2, out, N);
}

// Round 4
// 285.602 us; speedup vs baseline: 2.0219x; 1.3084x over previous
//
#include <hip/hip_runtime.h>

#define EPS 1e-5f
#define SLOPE 0.01f

typedef short bf16x8 __attribute__((ext_vector_type(8)));
typedef float f32x4 __attribute__((ext_vector_type(4)));

static __device__ __forceinline__ unsigned short f2bf(float f) {
  unsigned u = __float_as_uint(f);
  unsigned r = (u + 0x7FFFu + ((u >> 16) & 1u)) >> 16;
  return (unsigned short)r;
}
static __device__ __forceinline__ float bf2f(unsigned short h) {
  return __uint_as_float(((unsigned)h) << 16);
}

// ================= CSR build: two-level counting sort =================
// bucket = dst >> 6 (64 nodes per bucket). Phase 1: per-block LDS histogram.
// Phase 2: scan [bucket][block]. Phase 3: scatter edges into bucket-sorted
// `binned` (contiguous per (block,bucket) stream -> ~1x write amp; src packed
// with dst&63 in 26 bits). Phase 4: per-bucket block builds rowptr + col from
// its contiguous segment (writes land in a ~4KB L2-resident window).

__global__ __launch_bounds__(1024) void hist_kernel(const int* __restrict__ dst,
                                                    int* __restrict__ hist,
                                                    int E, int NB) {
  extern __shared__ int lh[];
  for (int i = threadIdx.x; i < NB; i += blockDim.x) lh[i] = 0;
  __syncthreads();
  int stride = gridDim.x * blockDim.x;
  for (int i = blockIdx.x * blockDim.x + threadIdx.x; i < E; i += stride)
    atomicAdd(&lh[((unsigned)dst[i]) >> 6], 1);
  __syncthreads();
  for (int b = threadIdx.x; b < NB; b += blockDim.x)
    hist[(size_t)b * gridDim.x + blockIdx.x] = lh[b];
}

// generic 3-step exclusive scan (in-place safe: reads complete before writes)
__global__ void scan_blk(const int* in, int* out, int* bsum, int n) {
  __shared__ int s[256];
  int i = blockIdx.x * 256 + threadIdx.x;
  int v = (i < n) ? in[i] : 0;
  s[threadIdx.x] = v;
  __syncthreads();
  for (int off = 1; off < 256; off <<= 1) {
    int t = (threadIdx.x >= off) ? s[threadIdx.x - off] : 0;
    __syncthreads();
    s[threadIdx.x] += t;
    __syncthreads();
  }
  if (i < n) out[i] = s[threadIdx.x] - v;
  if (threadIdx.x == 255) bsum[blockIdx.x] = s[255];
}

__global__ void scan_top(int* bsum, int nb) {
  __shared__ int s[512];
  int tid = threadIdx.x;
  int v = (tid < nb) ? bsum[tid] : 0;
  s[tid] = v;
  __syncthreads();
  for (int off = 1; off < 512; off <<= 1) {
    int t = (tid >= off) ? s[tid - off] : 0;
    __syncthreads();
    s[tid] += t;
    __syncthreads();
  }
  if (tid < nb) bsum[tid] = s[tid] - v;
}

__global__ void scan_add(int* out, const int* bsum, int n) {
  int i = blockIdx.x * 256 + threadIdx.x;
  if (i < n) out[i] += bsum[blockIdx.x];
}

__global__ __launch_bounds__(1024) void scatter_kernel(
    const int* __restrict__ src, const int* __restrict__ dst,
    const int* __restrict__ histS, unsigned* __restrict__ binned, int E, int NB) {
  extern __shared__ int cur[];
  for (int b = threadIdx.x; b < NB; b += blockDim.x)
    cur[b] = histS[(size_t)b * gridDim.x + blockIdx.x];
  __syncthreads();
  int stride = gridDim.x * blockDim.x;
  for (int i = blockIdx.x * blockDim.x + threadIdx.x; i < E; i += stride) {
    int d = dst[i];
    unsigned s = (unsigned)src[i];
    int b = ((unsigned)d) >> 6;
    int pos = atomicAdd(&cur[b], 1);
    binned[pos] = s | (((unsigned)d & 63u) << 20);  // requires N <= 2^20
  }
}

__global__ __launch_bounds__(256) void fine_kernel(
    const unsigned* __restrict__ binned, const int* __restrict__ histS,
    int* __restrict__ rowptr, int* __restrict__ col, int E, int NB, int NBLKB, int N) {
  __shared__ int ldeg[64];
  __shared__ int lcur[64];
  int b = blockIdx.x;
  int seg_s = histS[(size_t)b * NBLKB];
  int seg_e = (b + 1 < NB) ? histS[(size_t)(b + 1) * NBLKB] : E;
  if (threadIdx.x < 64) ldeg[threadIdx.x] = 0;
  __syncthreads();
  for (int i = seg_s + threadIdx.x; i < seg_e; i += 256)
    atomicAdd(&ldeg[binned[i] >> 20], 1);
  __syncthreads();
  if (threadIdx.x < 64) {  // wave 0: exclusive scan of 64 degrees
    int d = ldeg[threadIdx.x];
    int x = d;
    #pragma unroll
    for (int o = 1; o < 64; o <<= 1) {
      int y = __shfl_up(x, o);
      if ((int)threadIdx.x >= o) x += y;
    }
    int base = seg_s + x - d;
    lcur[threadIdx.x] = base;
    int node = (b << 6) + threadIdx.x;
    if (node <= N) rowptr[node] = base;
  }
  __syncthreads();
  for (int i = seg_s + threadIdx.x; i < seg_e; i += 256) {
    unsigned v = binned[i];
    int pos = atomicAdd(&lcur[v >> 20], 1);
    col[pos] = (int)(v & 0xFFFFFu);
  }
}

__global__ void sentinel_kernel(int* rowptr, int N, int E) {
  rowptr[N] = E;  // duplicate-equal write when N%64!=0; required when N%64==0
}

// ---------------- f32 -> bf16 conversion ----------------

__global__ void cvt_kernel(const float* __restrict__ x, unsigned short* __restrict__ xb,
                           int total4) {
  int stride = gridDim.x * blockDim.x;
  for (int i = blockIdx.x * blockDim.x + threadIdx.x; i < total4; i += stride) {
    float4 v = reinterpret_cast<const float4*>(x)[i];
    ushort4 o;
    o.x = f2bf(v.x); o.y = f2bf(v.y); o.z = f2bf(v.z); o.w = f2bf(v.w);
    reinterpret_cast<ushort4*>(xb)[i] = o;
  }
}

// ---------------- neighbor mean (pull, wave-per-node, 4 rows/instr) ----------------

__global__ void agg_kernel(const unsigned short* __restrict__ hb,
                           const int* __restrict__ rowptr,
                           const int* __restrict__ col,
                           unsigned short* __restrict__ hm, int n) {
  int node = (blockIdx.x * blockDim.x + threadIdx.x) >> 6;
  int lane = threadIdx.x & 63;
  if (node >= n) return;
  int beg = rowptr[node];
  int end = rowptr[node + 1];
  int qr = lane >> 4;        // 0..3: which neighbor in the group of 4
  int fo = (lane & 15) * 4;  // feature offset: 4 feats per lane
  float s0 = 0.f, s1 = 0.f, s2 = 0.f, s3 = 0.f;
  for (int base = beg; base < end; base += 64) {
    int cnt = min(64, end - base);
    int cidx = (base + lane < end) ? col[base + lane] : 0;
    for (int j = 0; j < cnt; j += 4) {
      int jj = j + qr;
      int idx = __shfl(cidx, jj);
      if (jj < cnt) {
        uint2 u = *reinterpret_cast<const uint2*>(&hb[(size_t)idx * 64 + fo]);
        s0 += __uint_as_float(u.x << 16);
        s1 += __uint_as_float(u.x & 0xFFFF0000u);
        s2 += __uint_as_float(u.y << 16);
        s3 += __uint_as_float(u.y & 0xFFFF0000u);
      }
    }
  }
  s0 += __shfl_xor(s0, 16); s1 += __shfl_xor(s1, 16);
  s2 += __shfl_xor(s2, 16); s3 += __shfl_xor(s3, 16);
  s0 += __shfl_xor(s0, 32); s1 += __shfl_xor(s1, 32);
  s2 += __shfl_xor(s2, 32); s3 += __shfl_xor(s3, 32);
  if (lane < 16) {
    int d = end - beg;
    float inv = 1.0f / (float)(d > 0 ? d : 1);
    ushort4 o;
    o.x = f2bf(s0 * inv); o.y = f2bf(s1 * inv);
    o.z = f2bf(s2 * inv); o.w = f2bf(s3 * inv);
    *reinterpret_cast<ushort4*>(&hm[(size_t)node * 64 + fo]) = o;
  }
}

// ---------------- MFMA GEMM: z = [A0|A1] @ [Wself|Wneigh]^T + b, + BN stats ----------------

#define LDK 136  // row stride in bf16 elements (272 B, conflict-free b128)

__global__ __launch_bounds__(256) void gemm_mfma(
    const unsigned short* __restrict__ A0,
    const unsigned short* __restrict__ A1,
    const float* __restrict__ Wself, const float* __restrict__ Wneigh,
    const float* __restrict__ bias,
    float* __restrict__ z, float* __restrict__ stats, int n) {
  __shared__ unsigned short X[64 * LDK];
  __shared__ unsigned short W[64 * LDK];
  __shared__ float sred[128];
  int tid = threadIdx.x;
  int rowbase = blockIdx.x * 64;

  #pragma unroll
  for (int it = 0; it < 4; ++it) {
    int c = tid + it * 256;
    int r = c >> 4;
    int half = (c >> 3) & 1;
    int off = (c & 7) * 8;
    int gr = rowbase + r;
    uint4 v = make_uint4(0u, 0u, 0u, 0u);
    if (gr < n) {
      const unsigned short* srcp = (half ? A1 : A0) + (size_t)gr * 64 + off;
      v = *reinterpret_cast<const uint4*>(srcp);
    }
    *reinterpret_cast<uint4*>(&X[r * LDK + half * 64 + off]) = v;

    const float* wp = (half ? Wneigh : Wself) + r * 64 + off;
    float4 w0 = *reinterpret_cast<const float4*>(wp);
    float4 w1 = *reinterpret_cast<const float4*>(wp + 4);
    ushort4 wa, wb;
    wa.x = f2bf(w0.x); wa.y = f2bf(w0.y); wa.z = f2bf(w0.z); wa.w = f2bf(w0.w);
    wb.x = f2bf(w1.x); wb.y = f2bf(w1.y); wb.z = f2bf(w1.z); wb.w = f2bf(w1.w);
    unsigned short* wd = &W[r * LDK + half * 64 + off];
    *reinterpret_cast<ushort4*>(wd) = wa;
    *reinterpret_cast<ushort4*>(wd + 4) = wb;
  }
  if (tid < 128) sred[tid] = 0.f;
  __syncthreads();

  int lane = tid & 63;
  int w = tid >> 6;
  int l15 = lane & 15;
  int g = lane >> 4;

  f32x4 acc[4] = {};
  #pragma unroll
  for (int s = 0; s < 4; ++s) {
    bf16x8 a = *reinterpret_cast<const bf16x8*>(&X[(w * 16 + l15) * LDK + s * 32 + g * 8]);
    #pragma unroll
    for (int t = 0; t < 4; ++t) {
      bf16x8 b = *reinterpret_cast<const bf16x8*>(&W[(t * 16 + l15) * LDK + s * 32 + g * 8]);
      acc[t] = __builtin_amdgcn_mfma_f32_16x16x32_bf16(a, b, acc[t], 0, 0, 0);
    }
  }

  #pragma unroll
  for (int t = 0; t < 4; ++t) {
    int f = t * 16 + l15;
    float bb = bias[f];
    float p1 = 0.f, p2 = 0.f;
    #pragma unroll
    for (int i = 0; i < 4; ++i) {
      int gr = rowbase + w * 16 + g * 4 + i;
      if (gr < n) {
        float v = acc[t][i] + bb;
        z[(size_t)gr * 64 + f] = v;
        p1 += v;
        p2 += v * v;
      }
    }
    atomicAdd(&sred[f], p1);
    atomicAdd(&sred[64 + f], p2);
  }
  __syncthreads();
  if (tid < 128) atomicAdd(&stats[tid], sred[tid]);
}

// ---------------- BN (affine) + leaky relu ----------------

__global__ void bn_bf16_kernel(const float* __restrict__ z, const float* __restrict__ stats,
                               const float* __restrict__ gamma, const float* __restrict__ beta,
                               unsigned short* __restrict__ out, int n) {
  __shared__ float sc[64];
  __shared__ float sh[64];
  if (threadIdx.x < 64) {
    int f = threadIdx.x;
    float invN = 1.0f / (float)n;
    float mu = stats[f] * invN;
    float var = stats[64 + f] * invN - mu * mu;
    float s = rsqrtf(var + EPS) * gamma[f];
    sc[f] = s;
    sh[f] = beta[f] - mu * s;
  }
  __syncthreads();
  int total = n * 16;
  int stride = gridDim.x * blockDim.x;
  for (int idx = blockIdx.x * blockDim.x + threadIdx.x; idx < total; idx += stride) {
    int f0 = (idx & 15) * 4;
    float4 v = reinterpret_cast<const float4*>(z)[idx];
    float t;
    ushort4 o;
    t = v.x * sc[f0 + 0] + sh[f0 + 0]; o.x = f2bf(t > 0.f ? t : SLOPE * t);
    t = v.y * sc[f0 + 1] + sh[f0 + 1]; o.y = f2bf(t > 0.f ? t : SLOPE * t);
    t = v.z * sc[f0 + 2] + sh[f0 + 2]; o.z = f2bf(t > 0.f ? t : SLOPE * t);
    t = v.w * sc[f0 + 3] + sh[f0 + 3]; o.w = f2bf(t > 0.f ? t : SLOPE * t);
    reinterpret_cast<ushort4*>(out)[idx] = o;
  }
}

__global__ void bn_f32_kernel(const float* __restrict__ z, const float* __restrict__ stats,
                              const float* __restrict__ gamma, const float* __restrict__ beta,
                              float* __restrict__ out, int n) {
  __shared__ float sc[64];
  __shared__ float sh[64];
  if (threadIdx.x < 64) {
    int f = threadIdx.x;
    float invN = 1.0f / (float)n;
    float mu = stats[f] * invN;
    float var = stats[64 + f] * invN - mu * mu;
    float s = rsqrtf(var + EPS) * gamma[f];
    sc[f] = s;
    sh[f] = beta[f] - mu * s;
  }
  __syncthreads();
  int total = n * 16;
  int stride = gridDim.x * blockDim.x;
  for (int idx = blockIdx.x * blockDim.x + threadIdx.x; idx < total; idx += stride) {
    int f0 = (idx & 15) * 4;
    float4 v = reinterpret_cast<const float4*>(z)[idx];
    float4 o;
    float t;
    t = v.x * sc[f0 + 0] + sh[f0 + 0]; o.x = t > 0.f ? t : SLOPE * t;
    t = v.y * sc[f0 + 1] + sh[f0 + 1]; o.y = t > 0.f ? t : SLOPE * t;
    t = v.z * sc[f0 + 2] + sh[f0 + 2]; o.z = t > 0.f ? t : SLOPE * t;
    t = v.w * sc[f0 + 3] + sh[f0 + 3]; o.w = t > 0.f ? t : SLOPE * t;
    reinterpret_cast<float4*>(out)[idx] = o;
  }
}

// ---------------- launch ----------------

extern "C" void kernel_launch(void* const* d_in, const int* in_sizes, int n_in,
                              void* d_out, int out_size, void* d_ws, size_t ws_size,
                              hipStream_t stream) {
  const float* x  = (const float*)d_in[0];
  const int* ei   = (const int*)d_in[1];
  const float* Ws1 = (const float*)d_in[2];
  const float* Wn1 = (const float*)d_in[3];
  const float* b1  = (const float*)d_in[4];
  const float* g1  = (const float*)d_in[5];
  const float* be1 = (const float*)d_in[6];
  const float* Ws2 = (const float*)d_in[7];
  const float* Wn2 = (const float*)d_in[8];
  const float* b2  = (const float*)d_in[9];
  const float* g2  = (const float*)d_in[10];
  const float* be2 = (const float*)d_in[11];
  float* out = (float*)d_out;

  int N = in_sizes[0] / 64;
  int E = in_sizes[1] / 2;
  const int* src = ei;
  const int* dst = ei + E;

  int NB = (N + 63) >> 6;       // buckets of 64 nodes
  const int NBLKB = 64;         // blocks in hist/scatter
  int M = NB * NBLKB;

  char* ws = (char*)d_ws;
  float* stats1 = (float*)ws;            // 128
  float* stats2 = stats1 + 128;          // 128
  size_t off = 1024;
  auto take = [&](size_t bytes) {
    void* p = ws + off;
    off = (off + bytes + 255) & ~(size_t)255;
    return p;
  };
  int* hist   = (int*)take((size_t)M * 4);
  int* bsum   = (int*)take(512 * 4);
  int* rowptr = (int*)take((size_t)(N + 1) * 4);
  unsigned* binned = (unsigned*)take((size_t)E * 4);
  int* col    = (int*)take((size_t)E * 4);
  unsigned short* xb  = (unsigned short*)take((size_t)N * 64 * 2);
  unsigned short* hmb = (unsigned short*)take((size_t)N * 64 * 2);
  unsigned short* h1b = (unsigned short*)take((size_t)N * 64 * 2);

  hipMemsetAsync(ws, 0, 1024, stream);  // stats only

  // CSR build
  hist_kernel<<<NBLKB, 1024, NB * 4, stream>>>(dst, hist, E, NB);
  int nb1 = (M + 255) / 256;
  scan_blk<<<nb1, 256, 0, stream>>>(hist, hist, bsum, M);
  scan_top<<<1, 512, 0, stream>>>(bsum, nb1);
  scan_add<<<nb1, 256, 0, stream>>>(hist, bsum, M);
  scatter_kernel<<<NBLKB, 1024, NB * 4, stream>>>(src, dst, hist, binned, E, NB);
  fine_kernel<<<NB, 256, 0, stream>>>(binned, hist, rowptr, col, E, NB, NBLKB, N);
  sentinel_kernel<<<1, 1, 0, stream>>>(rowptr, N, E);

  cvt_kernel<<<1024, 256, 0, stream>>>(x, xb, N * 16);

  int ab = (N + 3) / 4;
  int gb = (N + 63) / 64;

  // layer 1 (z staged in d_out)
  agg_kernel<<<ab, 256, 0, stream>>>(xb, rowptr, col, hmb, N);
  gemm_mfma<<<gb, 256, 0, stream>>>(xb, hmb, Ws1, Wn1, b1, out, stats1, N);
  bn_bf16_kernel<<<2048, 256, 0, stream>>>(out, stats1, g1, be1, h1b, N);

  // layer 2
  agg_kernel<<<ab, 256, 0, stream>>>(h1b, rowptr, col, hmb, N);
  gemm_mfma<<<gb, 256, 0, stream>>>(h1b, hmb, Ws2, Wn2, b2, out, stats2, N);
  bn_f32_kernel<<<2048, 256, 0, stream>>>(out, stats2, g2, be2, out, N);
}

// Round 5
// 238.064 us; speedup vs baseline: 2.4256x; 1.1997x over previous
//
#include <hip/hip_runtime.h>

#define EPS 1e-5f
#define SLOPE 0.01f

typedef short bf16x8 __attribute__((ext_vector_type(8)));
typedef float f32x4 __attribute__((ext_vector_type(4)));

static __device__ __forceinline__ unsigned short f2bf(float f) {
  unsigned u = __float_as_uint(f);
  unsigned r = (u + 0x7FFFu + ((u >> 16) & 1u)) >> 16;
  return (unsigned short)r;
}

// ================= CSR build: two-level counting sort =================

__global__ __launch_bounds__(1024) void hist_kernel(const int* __restrict__ dst,
                                                    int* __restrict__ hist,
                                                    int E, int NB) {
  extern __shared__ int lh[];
  for (int i = threadIdx.x; i < NB; i += blockDim.x) lh[i] = 0;
  __syncthreads();
  int stride = gridDim.x * blockDim.x;
  for (int i = blockIdx.x * blockDim.x + threadIdx.x; i < E; i += stride)
    atomicAdd(&lh[((unsigned)dst[i]) >> 6], 1);
  __syncthreads();
  for (int b = threadIdx.x; b < NB; b += blockDim.x)
    hist[(size_t)b * gridDim.x + blockIdx.x] = lh[b];
}

__global__ void scan_blk(const int* in, int* out, int* bsum, int n) {
  __shared__ int s[256];
  int i = blockIdx.x * 256 + threadIdx.x;
  int v = (i < n) ? in[i] : 0;
  s[threadIdx.x] = v;
  __syncthreads();
  for (int off = 1; off < 256; off <<= 1) {
    int t = (threadIdx.x >= off) ? s[threadIdx.x - off] : 0;
    __syncthreads();
    s[threadIdx.x] += t;
    __syncthreads();
  }
  if (i < n) out[i] = s[threadIdx.x] - v;
  if (threadIdx.x == 255) bsum[blockIdx.x] = s[255];
}

__global__ void scan_top(int* bsum, int nb) {
  __shared__ int s[512];
  int tid = threadIdx.x;
  int v = (tid < nb) ? bsum[tid] : 0;
  s[tid] = v;
  __syncthreads();
  for (int off = 1; off < 512; off <<= 1) {
    int t = (tid >= off) ? s[tid - off] : 0;
    __syncthreads();
    s[tid] += t;
    __syncthreads();
  }
  if (tid < nb) bsum[tid] = s[tid] - v;
}

__global__ void scan_add(int* out, const int* bsum, int n) {
  int i = blockIdx.x * 256 + threadIdx.x;
  if (i < n) out[i] += bsum[blockIdx.x];
}

__global__ __launch_bounds__(1024) void scatter_kernel(
    const int* __restrict__ src, const int* __restrict__ dst,
    const int* __restrict__ histS, unsigned* __restrict__ binned, int E, int NB) {
  extern __shared__ int cur[];
  for (int b = threadIdx.x; b < NB; b += blockDim.x)
    cur[b] = histS[(size_t)b * gridDim.x + blockIdx.x];
  __syncthreads();
  int stride = gridDim.x * blockDim.x;
  for (int i = blockIdx.x * blockDim.x + threadIdx.x; i < E; i += stride) {
    int d = dst[i];
    unsigned s = (unsigned)src[i];
    int b = ((unsigned)d) >> 6;
    int pos = atomicAdd(&cur[b], 1);
    binned[pos] = s | (((unsigned)d & 63u) << 20);  // requires N <= 2^20
  }
}

__global__ __launch_bounds__(256) void fine_kernel(
    const unsigned* __restrict__ binned, const int* __restrict__ histS,
    int* __restrict__ rowptr, int* __restrict__ col, int E, int NB, int NBLKB, int N) {
  __shared__ int ldeg[64];
  __shared__ int lcur[64];
  int b = blockIdx.x;
  int seg_s = histS[(size_t)b * NBLKB];
  int seg_e = (b + 1 < NB) ? histS[(size_t)(b + 1) * NBLKB] : E;
  if (threadIdx.x < 64) ldeg[threadIdx.x] = 0;
  __syncthreads();
  for (int i = seg_s + threadIdx.x; i < seg_e; i += 256)
    atomicAdd(&ldeg[binned[i] >> 20], 1);
  __syncthreads();
  if (threadIdx.x < 64) {
    int d = ldeg[threadIdx.x];
    int x = d;
    #pragma unroll
    for (int o = 1; o < 64; o <<= 1) {
      int y = __shfl_up(x, o);
      if ((int)threadIdx.x >= o) x += y;
    }
    int base = seg_s + x - d;
    lcur[threadIdx.x] = base;
    int node = (b << 6) + threadIdx.x;
    if (node <= N) rowptr[node] = base;
  }
  __syncthreads();
  for (int i = seg_s + threadIdx.x; i < seg_e; i += 256) {
    unsigned v = binned[i];
    int pos = atomicAdd(&lcur[v >> 20], 1);
    col[pos] = (int)(v & 0xFFFFFu);
  }
}

__global__ void sentinel_kernel(int* rowptr, int N, int E) {
  rowptr[N] = E;
}

// ---------------- f32 -> bf16 conversion ----------------

__global__ void cvt_kernel(const float* __restrict__ x, unsigned short* __restrict__ xb,
                           int total4) {
  int stride = gridDim.x * blockDim.x;
  for (int i = blockIdx.x * blockDim.x + threadIdx.x; i < total4; i += stride) {
    float4 v = reinterpret_cast<const float4*>(x)[i];
    ushort4 o;
    o.x = f2bf(v.x); o.y = f2bf(v.y); o.z = f2bf(v.z); o.w = f2bf(v.w);
    reinterpret_cast<ushort4*>(xb)[i] = o;
  }
}

// ---------------- neighbor mean (pull, wave-per-node, 4 rows/instr) ----------------

__global__ void agg_kernel(const unsigned short* __restrict__ hb,
                           const int* __restrict__ rowptr,
                           const int* __restrict__ col,
                           unsigned short* __restrict__ hm, int n) {
  int node = (blockIdx.x * blockDim.x + threadIdx.x) >> 6;
  int lane = threadIdx.x & 63;
  if (node >= n) return;
  int beg = rowptr[node];
  int end = rowptr[node + 1];
  int qr = lane >> 4;
  int fo = (lane & 15) * 4;
  float s0 = 0.f, s1 = 0.f, s2 = 0.f, s3 = 0.f;
  for (int base = beg; base < end; base += 64) {
    int cnt = min(64, end - base);
    int cidx = (base + lane < end) ? col[base + lane] : 0;
    for (int j = 0; j < cnt; j += 4) {
      int jj = j + qr;
      int idx = __shfl(cidx, jj);
      if (jj < cnt) {
        uint2 u = *reinterpret_cast<const uint2*>(&hb[(size_t)idx * 64 + fo]);
        s0 += __uint_as_float(u.x << 16);
        s1 += __uint_as_float(u.x & 0xFFFF0000u);
        s2 += __uint_as_float(u.y << 16);
        s3 += __uint_as_float(u.y & 0xFFFF0000u);
      }
    }
  }
  s0 += __shfl_xor(s0, 16); s1 += __shfl_xor(s1, 16);
  s2 += __shfl_xor(s2, 16); s3 += __shfl_xor(s3, 16);
  s0 += __shfl_xor(s0, 32); s1 += __shfl_xor(s1, 32);
  s2 += __shfl_xor(s2, 32); s3 += __shfl_xor(s3, 32);
  if (lane < 16) {
    int d = end - beg;
    float inv = 1.0f / (float)(d > 0 ? d : 1);
    ushort4 o;
    o.x = f2bf(s0 * inv); o.y = f2bf(s1 * inv);
    o.z = f2bf(s2 * inv); o.w = f2bf(s3 * inv);
    *reinterpret_cast<ushort4*>(&hm[(size_t)node * 64 + fo]) = o;
  }
}

// ========== streaming MFMA GEMM: no LDS staging, no hot-loop barriers ==========
// z[r][f] = b[f] + sum_k [A0|A1][r][k] * [Wself|Wneigh][f][k]
// W held in registers (16 bf16x8 frags); A-frags loaded directly from global.
// Per-wave 16-row tiles, wave-strided. BN partial sums in registers ->
// LDS reduce -> nonatomic per-block partial[128]; reduce_stats sums them.

__global__ __launch_bounds__(256) void gemm_stream(
    const unsigned short* __restrict__ A0,
    const unsigned short* __restrict__ A1,
    const float* __restrict__ Wself, const float* __restrict__ Wneigh,
    const float* __restrict__ bias,
    float* __restrict__ z, float* __restrict__ partial, int n, int ntiles) {
  int tid = threadIdx.x;
  int lane = tid & 63;
  int w = tid >> 6;
  int l15 = lane & 15;
  int g = lane >> 4;

  // B fragments: B[t][s] = W'[t*16+l15][s*32+g*8 .. +7], W' = [Wself|Wneigh]
  bf16x8 B[4][4];
  #pragma unroll
  for (int t = 0; t < 4; ++t) {
    #pragma unroll
    for (int s = 0; s < 4; ++s) {
      const float* base = (s < 2 ? Wself : Wneigh) + (t * 16 + l15) * 64 + (s & 1) * 32 + g * 8;
      float4 w0 = *reinterpret_cast<const float4*>(base);
      float4 w1 = *reinterpret_cast<const float4*>(base + 4);
      bf16x8 b;
      b[0] = (short)f2bf(w0.x); b[1] = (short)f2bf(w0.y);
      b[2] = (short)f2bf(w0.z); b[3] = (short)f2bf(w0.w);
      b[4] = (short)f2bf(w1.x); b[5] = (short)f2bf(w1.y);
      b[6] = (short)f2bf(w1.z); b[7] = (short)f2bf(w1.w);
      B[t][s] = b;
    }
  }
  float bv[4];
  #pragma unroll
  for (int t = 0; t < 4; ++t) bv[t] = bias[t * 16 + l15];

  float ps[4] = {0.f, 0.f, 0.f, 0.f};
  float pq[4] = {0.f, 0.f, 0.f, 0.f};

  int nw = gridDim.x * 4;
  for (int tile = blockIdx.x * 4 + w; tile < ntiles; tile += nw) {
    int r0 = tile * 16 + l15;  // row this lane loads A from
    uint4 a[4];
    if (r0 < n) {
      const uint4* pa0 = reinterpret_cast<const uint4*>(A0 + (size_t)r0 * 64);
      const uint4* pa1 = reinterpret_cast<const uint4*>(A1 + (size_t)r0 * 64);
      a[0] = pa0[g]; a[1] = pa0[4 + g]; a[2] = pa1[g]; a[3] = pa1[4 + g];
    } else {
      a[0] = a[1] = a[2] = a[3] = make_uint4(0u, 0u, 0u, 0u);
    }
    f32x4 acc[4] = {};
    #pragma unroll
    for (int s = 0; s < 4; ++s) {
      bf16x8 af = *reinterpret_cast<bf16x8*>(&a[s]);
      #pragma unroll
      for (int t = 0; t < 4; ++t)
        acc[t] = __builtin_amdgcn_mfma_f32_16x16x32_bf16(af, B[t][s], acc[t], 0, 0, 0);
    }
    #pragma unroll
    for (int t = 0; t < 4; ++t) {
      #pragma unroll
      for (int i = 0; i < 4; ++i) {
        int gr = tile * 16 + g * 4 + i;
        if (gr < n) {
          float v = acc[t][i] + bv[t];
          z[(size_t)gr * 64 + t * 16 + l15] = v;
          ps[t] += v;
          pq[t] += v * v;
        }
      }
    }
  }

  // reduce stats: lanes with same l15 within wave, then across waves via LDS
  #pragma unroll
  for (int t = 0; t < 4; ++t) {
    ps[t] += __shfl_xor(ps[t], 16); ps[t] += __shfl_xor(ps[t], 32);
    pq[t] += __shfl_xor(pq[t], 16); pq[t] += __shfl_xor(pq[t], 32);
  }
  __shared__ float sred[128];
  if (tid < 128) sred[tid] = 0.f;
  __syncthreads();
  if (lane < 16) {
    #pragma unroll
    for (int t = 0; t < 4; ++t) {
      atomicAdd(&sred[t * 16 + l15], ps[t]);
      atomicAdd(&sred[64 + t * 16 + l15], pq[t]);
    }
  }
  __syncthreads();
  if (tid < 128) partial[(size_t)blockIdx.x * 128 + tid] = sred[tid];
}

// sum partial[b][f] over blocks -> stats[f]   (grid = 128)
__global__ __launch_bounds__(256) void reduce_stats(const float* __restrict__ partial,
                                                    float* __restrict__ stats, int nblk) {
  int f = blockIdx.x;
  float s = 0.f;
  for (int j = threadIdx.x; j < nblk; j += 256) s += partial[(size_t)j * 128 + f];
  #pragma unroll
  for (int o = 1; o < 64; o <<= 1) s += __shfl_xor(s, o);
  __shared__ float r[4];
  if ((threadIdx.x & 63) == 0) r[threadIdx.x >> 6] = s;
  __syncthreads();
  if (threadIdx.x == 0) stats[f] = r[0] + r[1] + r[2] + r[3];
}

// ---------------- BN (affine) + leaky relu ----------------

__global__ void bn_bf16_kernel(const float* __restrict__ z, const float* __restrict__ stats,
                               const float* __restrict__ gamma, const float* __restrict__ beta,
                               unsigned short* __restrict__ out, int n) {
  __shared__ float sc[64];
  __shared__ float sh[64];
  if (threadIdx.x < 64) {
    int f = threadIdx.x;
    float invN = 1.0f / (float)n;
    float mu = stats[f] * invN;
    float var = stats[64 + f] * invN - mu * mu;
    float s = rsqrtf(var + EPS) * gamma[f];
    sc[f] = s;
    sh[f] = beta[f] - mu * s;
  }
  __syncthreads();
  int total = n * 16;
  int stride = gridDim.x * blockDim.x;
  for (int idx = blockIdx.x * blockDim.x + threadIdx.x; idx < total; idx += stride) {
    int f0 = (idx & 15) * 4;
    float4 v = reinterpret_cast<const float4*>(z)[idx];
    float t;
    ushort4 o;
    t = v.x * sc[f0 + 0] + sh[f0 + 0]; o.x = f2bf(t > 0.f ? t : SLOPE * t);
    t = v.y * sc[f0 + 1] + sh[f0 + 1]; o.y = f2bf(t > 0.f ? t : SLOPE * t);
    t = v.z * sc[f0 + 2] + sh[f0 + 2]; o.z = f2bf(t > 0.f ? t : SLOPE * t);
    t = v.w * sc[f0 + 3] + sh[f0 + 3]; o.w = f2bf(t > 0.f ? t : SLOPE * t);
    reinterpret_cast<ushort4*>(out)[idx] = o;
  }
}

__global__ void bn_f32_kernel(const float* __restrict__ z, const float* __restrict__ stats,
                              const float* __restrict__ gamma, const float* __restrict__ beta,
                              float* __restrict__ out, int n) {
  __shared__ float sc[64];
  __shared__ float sh[64];
  if (threadIdx.x < 64) {
    int f = threadIdx.x;
    float invN = 1.0f / (float)n;
    float mu = stats[f] * invN;
    float var = stats[64 + f] * invN - mu * mu;
    float s = rsqrtf(var + EPS) * gamma[f];
    sc[f] = s;
    sh[f] = beta[f] - mu * s;
  }
  __syncthreads();
  int total = n * 16;
  int stride = gridDim.x * blockDim.x;
  for (int idx = blockIdx.x * blockDim.x + threadIdx.x; idx < total; idx += stride) {
    int f0 = (idx & 15) * 4;
    float4 v = reinterpret_cast<const float4*>(z)[idx];
    float4 o;
    float t;
    t = v.x * sc[f0 + 0] + sh[f0 + 0]; o.x = t > 0.f ? t : SLOPE * t;
    t = v.y * sc[f0 + 1] + sh[f0 + 1]; o.y = t > 0.f ? t : SLOPE * t;
    t = v.z * sc[f0 + 2] + sh[f0 + 2]; o.z = t > 0.f ? t : SLOPE * t;
    t = v.w * sc[f0 + 3] + sh[f0 + 3]; o.w = t > 0.f ? t : SLOPE * t;
    reinterpret_cast<float4*>(out)[idx] = o;
  }
}

// ---------------- launch ----------------

extern "C" void kernel_launch(void* const* d_in, const int* in_sizes, int n_in,
                              void* d_out, int out_size, void* d_ws, size_t ws_size,
                              hipStream_t stream) {
  const float* x  = (const float*)d_in[0];
  const int* ei   = (const int*)d_in[1];
  const float* Ws1 = (const float*)d_in[2];
  const float* Wn1 = (const float*)d_in[3];
  const float* b1  = (const float*)d_in[4];
  const float* g1  = (const float*)d_in[5];
  const float* be1 = (const float*)d_in[6];
  const float* Ws2 = (const float*)d_in[7];
  const float* Wn2 = (const float*)d_in[8];
  const float* b2  = (const float*)d_in[9];
  const float* g2  = (const float*)d_in[10];
  const float* be2 = (const float*)d_in[11];
  float* out = (float*)d_out;

  int N = in_sizes[0] / 64;
  int E = in_sizes[1] / 2;
  const int* src = ei;
  const int* dst = ei + E;

  int NB = (N + 63) >> 6;
  const int NBLKB = 64;
  int M = NB * NBLKB;

  int ntiles = (N + 15) / 16;
  int gblk = (ntiles + 7) / 8;   // 4 waves/block, ~2 tiles/wave

  char* ws = (char*)d_ws;
  float* stats1 = (float*)ws;            // 128
  float* stats2 = stats1 + 128;          // 128
  size_t off = 1024;
  auto take = [&](size_t bytes) {
    void* p = ws + off;
    off = (off + bytes + 255) & ~(size_t)255;
    return p;
  };
  int* hist   = (int*)take((size_t)M * 4);
  int* bsum   = (int*)take(512 * 4);
  int* rowptr = (int*)take((size_t)(N + 1) * 4);
  unsigned* binned = (unsigned*)take((size_t)E * 4);
  int* col    = (int*)take((size_t)E * 4);
  unsigned short* xb  = (unsigned short*)take((size_t)N * 64 * 2);
  unsigned short* hmb = (unsigned short*)take((size_t)N * 64 * 2);
  unsigned short* h1b = (unsigned short*)take((size_t)N * 64 * 2);
  float* partial = (float*)take((size_t)gblk * 128 * 4);

  hipMemsetAsync(ws, 0, 1024, stream);  // stats only

  // CSR build
  hist_kernel<<<NBLKB, 1024, NB * 4, stream>>>(dst, hist, E, NB);
  int nb1 = (M + 255) / 256;
  scan_blk<<<nb1, 256, 0, stream>>>(hist, hist, bsum, M);
  scan_top<<<1, 512, 0, stream>>>(bsum, nb1);
  scan_add<<<nb1, 256, 0, stream>>>(hist, bsum, M);
  scatter_kernel<<<NBLKB, 1024, NB * 4, stream>>>(src, dst, hist, binned, E, NB);
  fine_kernel<<<NB, 256, 0, stream>>>(binned, hist, rowptr, col, E, NB, NBLKB, N);
  sentinel_kernel<<<1, 1, 0, stream>>>(rowptr, N, E);

  cvt_kernel<<<1024, 256, 0, stream>>>(x, xb, N * 16);

  int ab = (N + 3) / 4;

  // layer 1 (z staged in d_out)
  agg_kernel<<<ab, 256, 0, stream>>>(xb, rowptr, col, hmb, N);
  gemm_stream<<<gblk, 256, 0, stream>>>(xb, hmb, Ws1, Wn1, b1, out, partial, N, ntiles);
  reduce_stats<<<128, 256, 0, stream>>>(partial, stats1, gblk);
  bn_bf16_kernel<<<2048, 256, 0, stream>>>(out, stats1, g1, be1, h1b, N);

  // layer 2
  agg_kernel<<<ab, 256, 0, stream>>>(h1b, rowptr, col, hmb, N);
  gemm_stream<<<gblk, 256, 0, stream>>>(h1b, hmb, Ws2, Wn2, b2, out, partial, N, ntiles);
  reduce_stats<<<128, 256, 0, stream>>>(partial, stats2, gblk);
  bn_f32_kernel<<<2048, 256, 0, stream>>>(out, stats2, g2, be2, out, N);
}

// Round 6
// 192.285 us; speedup vs baseline: 3.0031x; 1.2381x over previous
//
#include <hip/hip_runtime.h>

#define EPS 1e-5f
#define SLOPE 0.01f

typedef short bf16x8 __attribute__((ext_vector_type(8)));
typedef float f32x4 __attribute__((ext_vector_type(4)));

static __device__ __forceinline__ unsigned short f2bf(float f) {
  unsigned u = __float_as_uint(f);
  unsigned r = (u + 0x7FFFu + ((u >> 16) & 1u)) >> 16;
  return (unsigned short)r;
}

// ================= CSR build: two-level counting sort =================
// bucket = dst >> 8 (256 nodes per bucket, NB=391). 256 hist/scatter blocks.
// binned = src | (dst&255)<<20  (needs N <= 2^20).

__global__ __launch_bounds__(1024) void hist_kernel(const int* __restrict__ dst,
                                                    int* __restrict__ hist,
                                                    int E, int NB) {
  extern __shared__ int lh[];
  for (int i = threadIdx.x; i < NB; i += blockDim.x) lh[i] = 0;
  __syncthreads();
  int stride = gridDim.x * blockDim.x;
  for (int i = blockIdx.x * blockDim.x + threadIdx.x; i < E; i += stride)
    atomicAdd(&lh[((unsigned)dst[i]) >> 8], 1);
  __syncthreads();
  for (int b = threadIdx.x; b < NB; b += blockDim.x)
    hist[(size_t)b * gridDim.x + blockIdx.x] = lh[b];
}

__global__ void scan_blk(const int* in, int* out, int* bsum, int n) {
  __shared__ int s[256];
  int i = blockIdx.x * 256 + threadIdx.x;
  int v = (i < n) ? in[i] : 0;
  s[threadIdx.x] = v;
  __syncthreads();
  for (int off = 1; off < 256; off <<= 1) {
    int t = (threadIdx.x >= off) ? s[threadIdx.x - off] : 0;
    __syncthreads();
    s[threadIdx.x] += t;
    __syncthreads();
  }
  if (i < n) out[i] = s[threadIdx.x] - v;
  if (threadIdx.x == 255) bsum[blockIdx.x] = s[255];
}

__global__ void scan_top(int* bsum, int nb) {
  __shared__ int s[512];
  int tid = threadIdx.x;
  int v = (tid < nb) ? bsum[tid] : 0;
  s[tid] = v;
  __syncthreads();
  for (int off = 1; off < 512; off <<= 1) {
    int t = (tid >= off) ? s[tid - off] : 0;
    __syncthreads();
    s[tid] += t;
    __syncthreads();
  }
  if (tid < nb) bsum[tid] = s[tid] - v;
}

__global__ void scan_add(int* out, const int* bsum, int n) {
  int i = blockIdx.x * 256 + threadIdx.x;
  if (i < n) out[i] += bsum[blockIdx.x];
}

__global__ __launch_bounds__(1024) void scatter_kernel(
    const int* __restrict__ src, const int* __restrict__ dst,
    const int* __restrict__ histS, unsigned* __restrict__ binned, int E, int NB) {
  extern __shared__ int cur[];
  for (int b = threadIdx.x; b < NB; b += blockDim.x)
    cur[b] = histS[(size_t)b * gridDim.x + blockIdx.x];
  __syncthreads();
  int stride = gridDim.x * blockDim.x;
  for (int i = blockIdx.x * blockDim.x + threadIdx.x; i < E; i += stride) {
    int d = dst[i];
    unsigned s = (unsigned)src[i];
    int b = ((unsigned)d) >> 8;
    int pos = atomicAdd(&cur[b], 1);
    binned[pos] = s | (((unsigned)d & 255u) << 20);
  }
}

__global__ __launch_bounds__(256) void fine_kernel(
    const unsigned* __restrict__ binned, const int* __restrict__ histS,
    int* __restrict__ rowptr, int* __restrict__ col, int E, int NB, int NBLKB, int N) {
  __shared__ int ldeg[256];
  __shared__ int lcur[256];
  __shared__ int ss[256];
  int b = blockIdx.x;
  int tid = threadIdx.x;
  int seg_s = histS[(size_t)b * NBLKB];
  int seg_e = (b + 1 < NB) ? histS[(size_t)(b + 1) * NBLKB] : E;
  ldeg[tid] = 0;
  __syncthreads();
  for (int i = seg_s + tid; i < seg_e; i += 256)
    atomicAdd(&ldeg[(binned[i] >> 20) & 255u], 1);
  __syncthreads();
  // block-wide exclusive scan of ldeg
  int d = ldeg[tid];
  ss[tid] = d;
  __syncthreads();
  for (int off = 1; off < 256; off <<= 1) {
    int t = (tid >= off) ? ss[tid - off] : 0;
    __syncthreads();
    ss[tid] += t;
    __syncthreads();
  }
  int base = seg_s + ss[tid] - d;
  lcur[tid] = base;
  int node = (b << 8) + tid;
  if (node < N) rowptr[node] = base;
  __syncthreads();
  for (int i = seg_s + tid; i < seg_e; i += 256) {
    unsigned v = binned[i];
    int pos = atomicAdd(&lcur[(v >> 20) & 255u], 1);
    col[pos] = (int)(v & 0xFFFFFu);
  }
}

__global__ void sentinel_kernel(int* rowptr, int N, int E) {
  rowptr[N] = E;
}

// ---------------- f32 -> bf16 conversion ----------------

__global__ void cvt_kernel(const float* __restrict__ x, unsigned short* __restrict__ xb,
                           int total4) {
  int stride = gridDim.x * blockDim.x;
  for (int i = blockIdx.x * blockDim.x + threadIdx.x; i < total4; i += stride) {
    float4 v = reinterpret_cast<const float4*>(x)[i];
    ushort4 o;
    o.x = f2bf(v.x); o.y = f2bf(v.y); o.z = f2bf(v.z); o.w = f2bf(v.w);
    reinterpret_cast<ushort4*>(xb)[i] = o;
  }
}

// ------- neighbor mean: 16 threads per node, broadcast col, no shfl -------
// Each 16-lane group owns one node; lane owns 4 features (uint2 slice).
// All 16 lanes read the same col[e] (broadcast, sequential, L1-hot); gather
// loads are independent across the unroll-4 body and across the 4 groups in
// a wave -> ~16 outstanding gathers/wave. No cross-lane reduction needed.

__global__ __launch_bounds__(256) void agg_kernel(
    const unsigned short* __restrict__ hb, const int* __restrict__ rowptr,
    const int* __restrict__ col, unsigned short* __restrict__ hm, int n) {
  int t = blockIdx.x * blockDim.x + threadIdx.x;
  int node = t >> 4;
  int fo = (t & 15) * 4;
  if (node >= n) return;
  int beg = rowptr[node];
  int end = rowptr[node + 1];
  float s0 = 0.f, s1 = 0.f, s2 = 0.f, s3 = 0.f;
  int e = beg;
  for (; e + 4 <= end; e += 4) {
    int i0 = col[e], i1 = col[e + 1], i2 = col[e + 2], i3 = col[e + 3];
    uint2 u0 = *reinterpret_cast<const uint2*>(&hb[(size_t)i0 * 64 + fo]);
    uint2 u1 = *reinterpret_cast<const uint2*>(&hb[(size_t)i1 * 64 + fo]);
    uint2 u2 = *reinterpret_cast<const uint2*>(&hb[(size_t)i2 * 64 + fo]);
    uint2 u3 = *reinterpret_cast<const uint2*>(&hb[(size_t)i3 * 64 + fo]);
    s0 += __uint_as_float(u0.x << 16) + __uint_as_float(u1.x << 16)
        + __uint_as_float(u2.x << 16) + __uint_as_float(u3.x << 16);
    s1 += __uint_as_float(u0.x & 0xFFFF0000u) + __uint_as_float(u1.x & 0xFFFF0000u)
        + __uint_as_float(u2.x & 0xFFFF0000u) + __uint_as_float(u3.x & 0xFFFF0000u);
    s2 += __uint_as_float(u0.y << 16) + __uint_as_float(u1.y << 16)
        + __uint_as_float(u2.y << 16) + __uint_as_float(u3.y << 16);
    s3 += __uint_as_float(u0.y & 0xFFFF0000u) + __uint_as_float(u1.y & 0xFFFF0000u)
        + __uint_as_float(u2.y & 0xFFFF0000u) + __uint_as_float(u3.y & 0xFFFF0000u);
  }
  for (; e < end; ++e) {
    uint2 u = *reinterpret_cast<const uint2*>(&hb[(size_t)col[e] * 64 + fo]);
    s0 += __uint_as_float(u.x << 16);
    s1 += __uint_as_float(u.x & 0xFFFF0000u);
    s2 += __uint_as_float(u.y << 16);
    s3 += __uint_as_float(u.y & 0xFFFF0000u);
  }
  int deg = end - beg;
  float inv = 1.0f / (float)(deg > 0 ? deg : 1);
  ushort4 o;
  o.x = f2bf(s0 * inv); o.y = f2bf(s1 * inv);
  o.z = f2bf(s2 * inv); o.w = f2bf(s3 * inv);
  *reinterpret_cast<ushort4*>(&hm[(size_t)node * 64 + fo]) = o;
}

// ========== streaming MFMA GEMM: no LDS staging, no hot-loop barriers ==========

__global__ __launch_bounds__(256) void gemm_stream(
    const unsigned short* __restrict__ A0,
    const unsigned short* __restrict__ A1,
    const float* __restrict__ Wself, const float* __restrict__ Wneigh,
    const float* __restrict__ bias,
    float* __restrict__ z, float* __restrict__ partial, int n, int ntiles) {
  int tid = threadIdx.x;
  int lane = tid & 63;
  int w = tid >> 6;
  int l15 = lane & 15;
  int g = lane >> 4;

  bf16x8 B[4][4];
  #pragma unroll
  for (int t = 0; t < 4; ++t) {
    #pragma unroll
    for (int s = 0; s < 4; ++s) {
      const float* base = (s < 2 ? Wself : Wneigh) + (t * 16 + l15) * 64 + (s & 1) * 32 + g * 8;
      float4 w0 = *reinterpret_cast<const float4*>(base);
      float4 w1 = *reinterpret_cast<const float4*>(base + 4);
      bf16x8 b;
      b[0] = (short)f2bf(w0.x); b[1] = (short)f2bf(w0.y);
      b[2] = (short)f2bf(w0.z); b[3] = (short)f2bf(w0.w);
      b[4] = (short)f2bf(w1.x); b[5] = (short)f2bf(w1.y);
      b[6] = (short)f2bf(w1.z); b[7] = (short)f2bf(w1.w);
      B[t][s] = b;
    }
  }
  float bv[4];
  #pragma unroll
  for (int t = 0; t < 4; ++t) bv[t] = bias[t * 16 + l15];

  float ps[4] = {0.f, 0.f, 0.f, 0.f};
  float pq[4] = {0.f, 0.f, 0.f, 0.f};

  int nw = gridDim.x * 4;
  for (int tile = blockIdx.x * 4 + w; tile < ntiles; tile += nw) {
    int r0 = tile * 16 + l15;
    uint4 a[4];
    if (r0 < n) {
      const uint4* pa0 = reinterpret_cast<const uint4*>(A0 + (size_t)r0 * 64);
      const uint4* pa1 = reinterpret_cast<const uint4*>(A1 + (size_t)r0 * 64);
      a[0] = pa0[g]; a[1] = pa0[4 + g]; a[2] = pa1[g]; a[3] = pa1[4 + g];
    } else {
      a[0] = a[1] = a[2] = a[3] = make_uint4(0u, 0u, 0u, 0u);
    }
    f32x4 acc[4] = {};
    #pragma unroll
    for (int s = 0; s < 4; ++s) {
      bf16x8 af = *reinterpret_cast<bf16x8*>(&a[s]);
      #pragma unroll
      for (int t = 0; t < 4; ++t)
        acc[t] = __builtin_amdgcn_mfma_f32_16x16x32_bf16(af, B[t][s], acc[t], 0, 0, 0);
    }
    #pragma unroll
    for (int t = 0; t < 4; ++t) {
      #pragma unroll
      for (int i = 0; i < 4; ++i) {
        int gr = tile * 16 + g * 4 + i;
        if (gr < n) {
          float v = acc[t][i] + bv[t];
          z[(size_t)gr * 64 + t * 16 + l15] = v;
          ps[t] += v;
          pq[t] += v * v;
        }
      }
    }
  }

  #pragma unroll
  for (int t = 0; t < 4; ++t) {
    ps[t] += __shfl_xor(ps[t], 16); ps[t] += __shfl_xor(ps[t], 32);
    pq[t] += __shfl_xor(pq[t], 16); pq[t] += __shfl_xor(pq[t], 32);
  }
  __shared__ float sred[128];
  if (tid < 128) sred[tid] = 0.f;
  __syncthreads();
  if (lane < 16) {
    #pragma unroll
    for (int t = 0; t < 4; ++t) {
      atomicAdd(&sred[t * 16 + l15], ps[t]);
      atomicAdd(&sred[64 + t * 16 + l15], pq[t]);
    }
  }
  __syncthreads();
  if (tid < 128) partial[(size_t)blockIdx.x * 128 + tid] = sred[tid];
}

__global__ __launch_bounds__(256) void reduce_stats(const float* __restrict__ partial,
                                                    float* __restrict__ stats, int nblk) {
  int f = blockIdx.x;
  float s = 0.f;
  for (int j = threadIdx.x; j < nblk; j += 256) s += partial[(size_t)j * 128 + f];
  #pragma unroll
  for (int o = 1; o < 64; o <<= 1) s += __shfl_xor(s, o);
  __shared__ float r[4];
  if ((threadIdx.x & 63) == 0) r[threadIdx.x >> 6] = s;
  __syncthreads();
  if (threadIdx.x == 0) stats[f] = r[0] + r[1] + r[2] + r[3];
}

// ---------------- BN (affine) + leaky relu ----------------

__global__ void bn_bf16_kernel(const float* __restrict__ z, const float* __restrict__ stats,
                               const float* __restrict__ gamma, const float* __restrict__ beta,
                               unsigned short* __restrict__ out, int n) {
  __shared__ float sc[64];
  __shared__ float sh[64];
  if (threadIdx.x < 64) {
    int f = threadIdx.x;
    float invN = 1.0f / (float)n;
    float mu = stats[f] * invN;
    float var = stats[64 + f] * invN - mu * mu;
    float s = rsqrtf(var + EPS) * gamma[f];
    sc[f] = s;
    sh[f] = beta[f] - mu * s;
  }
  __syncthreads();
  int total = n * 16;
  int stride = gridDim.x * blockDim.x;
  for (int idx = blockIdx.x * blockDim.x + threadIdx.x; idx < total; idx += stride) {
    int f0 = (idx & 15) * 4;
    float4 v = reinterpret_cast<const float4*>(z)[idx];
    float t;
    ushort4 o;
    t = v.x * sc[f0 + 0] + sh[f0 + 0]; o.x = f2bf(t > 0.f ? t : SLOPE * t);
    t = v.y * sc[f0 + 1] + sh[f0 + 1]; o.y = f2bf(t > 0.f ? t : SLOPE * t);
    t = v.z * sc[f0 + 2] + sh[f0 + 2]; o.z = f2bf(t > 0.f ? t : SLOPE * t);
    t = v.w * sc[f0 + 3] + sh[f0 + 3]; o.w = f2bf(t > 0.f ? t : SLOPE * t);
    reinterpret_cast<ushort4*>(out)[idx] = o;
  }
}

__global__ void bn_f32_kernel(const float* __restrict__ z, const float* __restrict__ stats,
                              const float* __restrict__ gamma, const float* __restrict__ beta,
                              float* __restrict__ out, int n) {
  __shared__ float sc[64];
  __shared__ float sh[64];
  if (threadIdx.x < 64) {
    int f = threadIdx.x;
    float invN = 1.0f / (float)n;
    float mu = stats[f] * invN;
    float var = stats[64 + f] * invN - mu * mu;
    float s = rsqrtf(var + EPS) * gamma[f];
    sc[f] = s;
    sh[f] = beta[f] - mu * s;
  }
  __syncthreads();
  int total = n * 16;
  int stride = gridDim.x * blockDim.x;
  for (int idx = blockIdx.x * blockDim.x + threadIdx.x; idx < total; idx += stride) {
    int f0 = (idx & 15) * 4;
    float4 v = reinterpret_cast<const float4*>(z)[idx];
    float4 o;
    float t;
    t = v.x * sc[f0 + 0] + sh[f0 + 0]; o.x = t > 0.f ? t : SLOPE * t;
    t = v.y * sc[f0 + 1] + sh[f0 + 1]; o.y = t > 0.f ? t : SLOPE * t;
    t = v.z * sc[f0 + 2] + sh[f0 + 2]; o.z = t > 0.f ? t : SLOPE * t;
    t = v.w * sc[f0 + 3] + sh[f0 + 3]; o.w = t > 0.f ? t : SLOPE * t;
    reinterpret_cast<float4*>(out)[idx] = o;
  }
}

// ---------------- launch ----------------

extern "C" void kernel_launch(void* const* d_in, const int* in_sizes, int n_in,
                              void* d_out, int out_size, void* d_ws, size_t ws_size,
                              hipStream_t stream) {
  const float* x  = (const float*)d_in[0];
  const int* ei   = (const int*)d_in[1];
  const float* Ws1 = (const float*)d_in[2];
  const float* Wn1 = (const float*)d_in[3];
  const float* b1  = (const float*)d_in[4];
  const float* g1  = (const float*)d_in[5];
  const float* be1 = (const float*)d_in[6];
  const float* Ws2 = (const float*)d_in[7];
  const float* Wn2 = (const float*)d_in[8];
  const float* b2  = (const float*)d_in[9];
  const float* g2  = (const float*)d_in[10];
  const float* be2 = (const float*)d_in[11];
  float* out = (float*)d_out;

  int N = in_sizes[0] / 64;
  int E = in_sizes[1] / 2;
  const int* src = ei;
  const int* dst = ei + E;

  int NB = (N + 255) >> 8;      // buckets of 256 nodes
  const int NBLKB = 256;        // blocks in hist/scatter
  int M = NB * NBLKB;

  int ntiles = (N + 15) / 16;
  int gblk = (ntiles + 7) / 8;

  char* ws = (char*)d_ws;
  float* stats1 = (float*)ws;            // 128
  float* stats2 = stats1 + 128;          // 128
  size_t off = 1024;
  auto take = [&](size_t bytes) {
    void* p = ws + off;
    off = (off + bytes + 255) & ~(size_t)255;
    return p;
  };
  int* hist   = (int*)take((size_t)M * 4);
  int* bsum   = (int*)take(512 * 4);
  int* rowptr = (int*)take((size_t)(N + 1) * 4);
  unsigned* binned = (unsigned*)take((size_t)E * 4);
  int* col    = (int*)take((size_t)E * 4);
  unsigned short* xb  = (unsigned short*)take((size_t)N * 64 * 2);
  unsigned short* hmb = (unsigned short*)take((size_t)N * 64 * 2);
  unsigned short* h1b = (unsigned short*)take((size_t)N * 64 * 2);
  float* partial = (float*)take((size_t)gblk * 128 * 4);

  hipMemsetAsync(ws, 0, 1024, stream);  // stats only

  // CSR build
  hist_kernel<<<NBLKB, 1024, NB * 4, stream>>>(dst, hist, E, NB);
  int nb1 = (M + 255) / 256;
  scan_blk<<<nb1, 256, 0, stream>>>(hist, hist, bsum, M);
  scan_top<<<1, 512, 0, stream>>>(bsum, nb1);
  scan_add<<<nb1, 256, 0, stream>>>(hist, bsum, M);
  scatter_kernel<<<NBLKB, 1024, NB * 4, stream>>>(src, dst, hist, binned, E, NB);
  fine_kernel<<<NB, 256, 0, stream>>>(binned, hist, rowptr, col, E, NB, NBLKB, N);
  sentinel_kernel<<<1, 1, 0, stream>>>(rowptr, N, E);

  cvt_kernel<<<1024, 256, 0, stream>>>(x, xb, N * 16);

  int ab = (N + 15) / 16;  // 16 nodes per 256-thread block

  // layer 1 (z staged in d_out)
  agg_kernel<<<ab, 256, 0, stream>>>(xb, rowptr, col, hmb, N);
  gemm_stream<<<gblk, 256, 0, stream>>>(xb, hmb, Ws1, Wn1, b1, out, partial, N, ntiles);
  reduce_stats<<<128, 256, 0, stream>>>(partial, stats1, gblk);
  bn_bf16_kernel<<<2048, 256, 0, stream>>>(out, stats1, g1, be1, h1b, N);

  // layer 2
  agg_kernel<<<ab, 256, 0, stream>>>(h1b, rowptr, col, hmb, N);
  gemm_stream<<<gblk, 256, 0, stream>>>(h1b, hmb, Ws2, Wn2, b2, out, partial, N, ntiles);
  reduce_stats<<<128, 256, 0, stream>>>(partial, stats2, gblk);
  bn_f32_kernel<<<2048, 256, 0, stream>>>(out, stats2, g2, be2, out, N);
}

// Round 7
// 173.761 us; speedup vs baseline: 3.3232x; 1.1066x over previous
//
#include <hip/hip_runtime.h>

#define EPS 1e-5f
#define SLOPE 0.01f

typedef short bf16x8 __attribute__((ext_vector_type(8)));
typedef float f32x4 __attribute__((ext_vector_type(4)));

static __device__ __forceinline__ unsigned short f2bf(float f) {
  unsigned u = __float_as_uint(f);
  unsigned r = (u + 0x7FFFu + ((u >> 16) & 1u)) >> 16;
  return (unsigned short)r;
}
#define BFLO(u) __uint_as_float((u) << 16)
#define BFHI(u) __uint_as_float((u) & 0xFFFF0000u)

// ================= CSR build: two-level counting sort =================
// bucket = dst >> 8 (256 nodes/bucket). hist fused with f32->bf16 cvt:
// blocks [0,histBlocks) do histogram, the rest convert x to bf16.

__global__ __launch_bounds__(1024) void hist_cvt_kernel(
    const int* __restrict__ dst, int* __restrict__ hist, int E, int NB,
    int histBlocks, const float* __restrict__ x, unsigned short* __restrict__ xb,
    int total4) {
  extern __shared__ int lh[];
  if ((int)blockIdx.x < histBlocks) {
    for (int i = threadIdx.x; i < NB; i += blockDim.x) lh[i] = 0;
    __syncthreads();
    int stride = histBlocks * blockDim.x;
    for (int i = blockIdx.x * blockDim.x + threadIdx.x; i < E; i += stride)
      atomicAdd(&lh[((unsigned)dst[i]) >> 8], 1);
    __syncthreads();
    for (int b = threadIdx.x; b < NB; b += blockDim.x)
      hist[(size_t)b * histBlocks + blockIdx.x] = lh[b];
  } else {
    int cb = blockIdx.x - histBlocks;
    int stride = (gridDim.x - histBlocks) * blockDim.x;
    for (int i = cb * blockDim.x + threadIdx.x; i < total4; i += stride) {
      float4 v = reinterpret_cast<const float4*>(x)[i];
      ushort4 o;
      o.x = f2bf(v.x); o.y = f2bf(v.y); o.z = f2bf(v.z); o.w = f2bf(v.w);
      reinterpret_cast<ushort4*>(xb)[i] = o;
    }
  }
}

__global__ void scan_blk(const int* in, int* out, int* bsum, int n) {
  __shared__ int s[256];
  int i = blockIdx.x * 256 + threadIdx.x;
  int v = (i < n) ? in[i] : 0;
  s[threadIdx.x] = v;
  __syncthreads();
  for (int off = 1; off < 256; off <<= 1) {
    int t = (threadIdx.x >= off) ? s[threadIdx.x - off] : 0;
    __syncthreads();
    s[threadIdx.x] += t;
    __syncthreads();
  }
  if (i < n) out[i] = s[threadIdx.x] - v;
  if (threadIdx.x == 255) bsum[blockIdx.x] = s[255];
}

__global__ void scan_top(int* bsum, int nb) {
  __shared__ int s[512];
  int tid = threadIdx.x;
  int v = (tid < nb) ? bsum[tid] : 0;
  s[tid] = v;
  __syncthreads();
  for (int off = 1; off < 512; off <<= 1) {
    int t = (tid >= off) ? s[tid - off] : 0;
    __syncthreads();
    s[tid] += t;
    __syncthreads();
  }
  if (tid < nb) bsum[tid] = s[tid] - v;
}

__global__ void scan_add(int* out, const int* bsum, int n) {
  int i = blockIdx.x * 256 + threadIdx.x;
  if (i < n) out[i] += bsum[blockIdx.x];
}

__global__ __launch_bounds__(1024) void scatter_kernel(
    const int* __restrict__ src, const int* __restrict__ dst,
    const int* __restrict__ histS, unsigned* __restrict__ binned, int E, int NB) {
  extern __shared__ int cur[];
  for (int b = threadIdx.x; b < NB; b += blockDim.x)
    cur[b] = histS[(size_t)b * gridDim.x + blockIdx.x];
  __syncthreads();
  int stride = gridDim.x * blockDim.x;
  for (int i = blockIdx.x * blockDim.x + threadIdx.x; i < E; i += stride) {
    int d = dst[i];
    unsigned s = (unsigned)src[i];
    int b = ((unsigned)d) >> 8;
    int pos = atomicAdd(&cur[b], 1);
    binned[pos] = s | (((unsigned)d & 255u) << 20);  // needs N <= 2^20
  }
}

__global__ __launch_bounds__(256) void fine_kernel(
    const unsigned* __restrict__ binned, const int* __restrict__ histS,
    int* __restrict__ rowptr, int* __restrict__ col, int E, int NB, int NBLKB, int N) {
  __shared__ int ldeg[256];
  __shared__ int lcur[256];
  __shared__ int ss[256];
  int b = blockIdx.x;
  int tid = threadIdx.x;
  int seg_s = histS[(size_t)b * NBLKB];
  int seg_e = (b + 1 < NB) ? histS[(size_t)(b + 1) * NBLKB] : E;
  ldeg[tid] = 0;
  __syncthreads();
  for (int i = seg_s + tid; i < seg_e; i += 256)
    atomicAdd(&ldeg[(binned[i] >> 20) & 255u], 1);
  __syncthreads();
  int d = ldeg[tid];
  ss[tid] = d;
  __syncthreads();
  for (int off = 1; off < 256; off <<= 1) {
    int t = (tid >= off) ? ss[tid - off] : 0;
    __syncthreads();
    ss[tid] += t;
    __syncthreads();
  }
  int base = seg_s + ss[tid] - d;
  lcur[tid] = base;
  int node = (b << 8) + tid;
  if (node < N) rowptr[node] = base;
  if (b == NB - 1 && tid == 0) rowptr[N] = E;  // sentinel
  __syncthreads();
  for (int i = seg_s + tid; i < seg_e; i += 256) {
    unsigned v = binned[i];
    int pos = atomicAdd(&lcur[(v >> 20) & 255u], 1);
    col[pos] = (int)(v & 0xFFFFFu);
  }
}

// ------- neighbor mean: 8 threads/node, uint4 gathers, broadcast col -------

__global__ __launch_bounds__(256) void agg_kernel(
    const unsigned short* __restrict__ hb, const int* __restrict__ rowptr,
    const int* __restrict__ col, unsigned short* __restrict__ hm, int n) {
  int t = blockIdx.x * 256 + threadIdx.x;
  int node = t >> 3;
  int fo = (t & 7) * 8;  // 8 features per lane
  if (node >= n) return;
  int beg = rowptr[node];
  int end = rowptr[node + 1];
  float s0 = 0.f, s1 = 0.f, s2 = 0.f, s3 = 0.f;
  float s4 = 0.f, s5 = 0.f, s6 = 0.f, s7 = 0.f;
  int e = beg;
  for (; e + 4 <= end; e += 4) {
    int i0 = col[e], i1 = col[e + 1], i2 = col[e + 2], i3 = col[e + 3];
    uint4 u0 = *reinterpret_cast<const uint4*>(&hb[(size_t)i0 * 64 + fo]);
    uint4 u1 = *reinterpret_cast<const uint4*>(&hb[(size_t)i1 * 64 + fo]);
    uint4 u2 = *reinterpret_cast<const uint4*>(&hb[(size_t)i2 * 64 + fo]);
    uint4 u3 = *reinterpret_cast<const uint4*>(&hb[(size_t)i3 * 64 + fo]);
    s0 += BFLO(u0.x) + BFLO(u1.x) + BFLO(u2.x) + BFLO(u3.x);
    s1 += BFHI(u0.x) + BFHI(u1.x) + BFHI(u2.x) + BFHI(u3.x);
    s2 += BFLO(u0.y) + BFLO(u1.y) + BFLO(u2.y) + BFLO(u3.y);
    s3 += BFHI(u0.y) + BFHI(u1.y) + BFHI(u2.y) + BFHI(u3.y);
    s4 += BFLO(u0.z) + BFLO(u1.z) + BFLO(u2.z) + BFLO(u3.z);
    s5 += BFHI(u0.z) + BFHI(u1.z) + BFHI(u2.z) + BFHI(u3.z);
    s6 += BFLO(u0.w) + BFLO(u1.w) + BFLO(u2.w) + BFLO(u3.w);
    s7 += BFHI(u0.w) + BFHI(u1.w) + BFHI(u2.w) + BFHI(u3.w);
  }
  for (; e < end; ++e) {
    uint4 u = *reinterpret_cast<const uint4*>(&hb[(size_t)col[e] * 64 + fo]);
    s0 += BFLO(u.x); s1 += BFHI(u.x);
    s2 += BFLO(u.y); s3 += BFHI(u.y);
    s4 += BFLO(u.z); s5 += BFHI(u.z);
    s6 += BFLO(u.w); s7 += BFHI(u.w);
  }
  int deg = end - beg;
  float inv = 1.0f / (float)(deg > 0 ? deg : 1);
  uint4 o;
  o.x = (unsigned)f2bf(s0 * inv) | ((unsigned)f2bf(s1 * inv) << 16);
  o.y = (unsigned)f2bf(s2 * inv) | ((unsigned)f2bf(s3 * inv) << 16);
  o.z = (unsigned)f2bf(s4 * inv) | ((unsigned)f2bf(s5 * inv) << 16);
  o.w = (unsigned)f2bf(s6 * inv) | ((unsigned)f2bf(s7 * inv) << 16);
  *reinterpret_cast<uint4*>(&hm[(size_t)node * 64 + fo]) = o;
}

// ========== streaming MFMA GEMM, bf16 z output ==========

__global__ __launch_bounds__(256) void gemm_stream(
    const unsigned short* __restrict__ A0,
    const unsigned short* __restrict__ A1,
    const float* __restrict__ Wself, const float* __restrict__ Wneigh,
    const float* __restrict__ bias,
    unsigned short* __restrict__ zb, float* __restrict__ partial, int n, int ntiles) {
  int tid = threadIdx.x;
  int lane = tid & 63;
  int w = tid >> 6;
  int l15 = lane & 15;
  int g = lane >> 4;

  bf16x8 B[4][4];
  #pragma unroll
  for (int t = 0; t < 4; ++t) {
    #pragma unroll
    for (int s = 0; s < 4; ++s) {
      const float* base = (s < 2 ? Wself : Wneigh) + (t * 16 + l15) * 64 + (s & 1) * 32 + g * 8;
      float4 w0 = *reinterpret_cast<const float4*>(base);
      float4 w1 = *reinterpret_cast<const float4*>(base + 4);
      bf16x8 b;
      b[0] = (short)f2bf(w0.x); b[1] = (short)f2bf(w0.y);
      b[2] = (short)f2bf(w0.z); b[3] = (short)f2bf(w0.w);
      b[4] = (short)f2bf(w1.x); b[5] = (short)f2bf(w1.y);
      b[6] = (short)f2bf(w1.z); b[7] = (short)f2bf(w1.w);
      B[t][s] = b;
    }
  }
  float bv[4];
  #pragma unroll
  for (int t = 0; t < 4; ++t) bv[t] = bias[t * 16 + l15];

  float ps[4] = {0.f, 0.f, 0.f, 0.f};
  float pq[4] = {0.f, 0.f, 0.f, 0.f};

  int nw = gridDim.x * 4;
  for (int tile = blockIdx.x * 4 + w; tile < ntiles; tile += nw) {
    int r0 = tile * 16 + l15;
    uint4 a[4];
    if (r0 < n) {
      const uint4* pa0 = reinterpret_cast<const uint4*>(A0 + (size_t)r0 * 64);
      const uint4* pa1 = reinterpret_cast<const uint4*>(A1 + (size_t)r0 * 64);
      a[0] = pa0[g]; a[1] = pa0[4 + g]; a[2] = pa1[g]; a[3] = pa1[4 + g];
    } else {
      a[0] = a[1] = a[2] = a[3] = make_uint4(0u, 0u, 0u, 0u);
    }
    f32x4 acc[4] = {};
    #pragma unroll
    for (int s = 0; s < 4; ++s) {
      bf16x8 af = *reinterpret_cast<bf16x8*>(&a[s]);
      #pragma unroll
      for (int t = 0; t < 4; ++t)
        acc[t] = __builtin_amdgcn_mfma_f32_16x16x32_bf16(af, B[t][s], acc[t], 0, 0, 0);
    }
    #pragma unroll
    for (int t = 0; t < 4; ++t) {
      #pragma unroll
      for (int i = 0; i < 4; ++i) {
        int gr = tile * 16 + g * 4 + i;
        if (gr < n) {
          float v = acc[t][i] + bv[t];
          zb[(size_t)gr * 64 + t * 16 + l15] = f2bf(v);
          ps[t] += v;
          pq[t] += v * v;
        }
      }
    }
  }

  #pragma unroll
  for (int t = 0; t < 4; ++t) {
    ps[t] += __shfl_xor(ps[t], 16); ps[t] += __shfl_xor(ps[t], 32);
    pq[t] += __shfl_xor(pq[t], 16); pq[t] += __shfl_xor(pq[t], 32);
  }
  __shared__ float sred[128];
  if (tid < 128) sred[tid] = 0.f;
  __syncthreads();
  if (lane < 16) {
    #pragma unroll
    for (int t = 0; t < 4; ++t) {
      atomicAdd(&sred[t * 16 + l15], ps[t]);
      atomicAdd(&sred[64 + t * 16 + l15], pq[t]);
    }
  }
  __syncthreads();
  if (tid < 128) partial[(size_t)blockIdx.x * 128 + tid] = sred[tid];
}

__global__ __launch_bounds__(256) void reduce_stats(const float* __restrict__ partial,
                                                    float* __restrict__ stats, int nblk) {
  int f = blockIdx.x;
  float s = 0.f;
  for (int j = threadIdx.x; j < nblk; j += 256) s += partial[(size_t)j * 128 + f];
  #pragma unroll
  for (int o = 1; o < 64; o <<= 1) s += __shfl_xor(s, o);
  __shared__ float r[4];
  if ((threadIdx.x & 63) == 0) r[threadIdx.x >> 6] = s;
  __syncthreads();
  if (threadIdx.x == 0) stats[f] = r[0] + r[1] + r[2] + r[3];
}

// ---------------- BN (affine) + leaky relu, bf16 z input ----------------

__global__ void bn_bf16_kernel(const unsigned short* __restrict__ zb,
                               const float* __restrict__ stats,
                               const float* __restrict__ gamma, const float* __restrict__ beta,
                               unsigned short* __restrict__ out, int n) {
  __shared__ float sc[64];
  __shared__ float sh[64];
  if (threadIdx.x < 64) {
    int f = threadIdx.x;
    float invN = 1.0f / (float)n;
    float mu = stats[f] * invN;
    float var = stats[64 + f] * invN - mu * mu;
    float s = rsqrtf(var + EPS) * gamma[f];
    sc[f] = s;
    sh[f] = beta[f] - mu * s;
  }
  __syncthreads();
  int total = n * 16;
  int stride = gridDim.x * blockDim.x;
  for (int idx = blockIdx.x * blockDim.x + threadIdx.x; idx < total; idx += stride) {
    int f0 = (idx & 15) * 4;
    uint2 u = reinterpret_cast<const uint2*>(zb)[idx];
    float t;
    ushort4 o;
    t = BFLO(u.x) * sc[f0 + 0] + sh[f0 + 0]; o.x = f2bf(t > 0.f ? t : SLOPE * t);
    t = BFHI(u.x) * sc[f0 + 1] + sh[f0 + 1]; o.y = f2bf(t > 0.f ? t : SLOPE * t);
    t = BFLO(u.y) * sc[f0 + 2] + sh[f0 + 2]; o.z = f2bf(t > 0.f ? t : SLOPE * t);
    t = BFHI(u.y) * sc[f0 + 3] + sh[f0 + 3]; o.w = f2bf(t > 0.f ? t : SLOPE * t);
    reinterpret_cast<ushort4*>(out)[idx] = o;
  }
}

__global__ void bn_f32_kernel(const unsigned short* __restrict__ zb,
                              const float* __restrict__ stats,
                              const float* __restrict__ gamma, const float* __restrict__ beta,
                              float* __restrict__ out, int n) {
  __shared__ float sc[64];
  __shared__ float sh[64];
  if (threadIdx.x < 64) {
    int f = threadIdx.x;
    float invN = 1.0f / (float)n;
    float mu = stats[f] * invN;
    float var = stats[64 + f] * invN - mu * mu;
    float s = rsqrtf(var + EPS) * gamma[f];
    sc[f] = s;
    sh[f] = beta[f] - mu * s;
  }
  __syncthreads();
  int total = n * 16;
  int stride = gridDim.x * blockDim.x;
  for (int idx = blockIdx.x * blockDim.x + threadIdx.x; idx < total; idx += stride) {
    int f0 = (idx & 15) * 4;
    uint2 u = reinterpret_cast<const uint2*>(zb)[idx];
    float4 o;
    float t;
    t = BFLO(u.x) * sc[f0 + 0] + sh[f0 + 0]; o.x = t > 0.f ? t : SLOPE * t;
    t = BFHI(u.x) * sc[f0 + 1] + sh[f0 + 1]; o.y = t > 0.f ? t : SLOPE * t;
    t = BFLO(u.y) * sc[f0 + 2] + sh[f0 + 2]; o.z = t > 0.f ? t : SLOPE * t;
    t = BFHI(u.y) * sc[f0 + 3] + sh[f0 + 3]; o.w = t > 0.f ? t : SLOPE * t;
    reinterpret_cast<float4*>(out)[idx] = o;
  }
}

// ---------------- launch ----------------

extern "C" void kernel_launch(void* const* d_in, const int* in_sizes, int n_in,
                              void* d_out, int out_size, void* d_ws, size_t ws_size,
                              hipStream_t stream) {
  const float* x  = (const float*)d_in[0];
  const int* ei   = (const int*)d_in[1];
  const float* Ws1 = (const float*)d_in[2];
  const float* Wn1 = (const float*)d_in[3];
  const float* b1  = (const float*)d_in[4];
  const float* g1  = (const float*)d_in[5];
  const float* be1 = (const float*)d_in[6];
  const float* Ws2 = (const float*)d_in[7];
  const float* Wn2 = (const float*)d_in[8];
  const float* b2  = (const float*)d_in[9];
  const float* g2  = (const float*)d_in[10];
  const float* be2 = (const float*)d_in[11];
  float* out = (float*)d_out;

  int N = in_sizes[0] / 64;
  int E = in_sizes[1] / 2;
  const int* src = ei;
  const int* dst = ei + E;

  int NB = (N + 255) >> 8;      // buckets of 256 nodes
  const int NBLKB = 256;        // hist/scatter parallel blocks
  int M = NB * NBLKB;

  int ntiles = (N + 15) / 16;
  int gblk = (ntiles + 7) / 8;

  char* ws = (char*)d_ws;
  float* stats1 = (float*)ws;            // 128 (overwritten by reduce_stats)
  float* stats2 = stats1 + 128;          // 128
  size_t off = 1024;
  auto take = [&](size_t bytes) {
    void* p = ws + off;
    off = (off + bytes + 255) & ~(size_t)255;
    return p;
  };
  int* hist   = (int*)take((size_t)M * 4);
  int* bsum   = (int*)take(512 * 4);
  int* rowptr = (int*)take((size_t)(N + 1) * 4);
  unsigned* binned = (unsigned*)take((size_t)E * 4);
  int* col    = (int*)take((size_t)E * 4);
  unsigned short* xb  = (unsigned short*)take((size_t)N * 64 * 2);
  unsigned short* hmb = (unsigned short*)take((size_t)N * 64 * 2);
  unsigned short* h1b = (unsigned short*)take((size_t)N * 64 * 2);
  unsigned short* zb  = (unsigned short*)take((size_t)N * 64 * 2);
  float* partial = (float*)take((size_t)gblk * 128 * 4);

  // CSR build + cvt (fused)
  hist_cvt_kernel<<<NBLKB + 128, 1024, NB * 4, stream>>>(dst, hist, E, NB, NBLKB,
                                                         x, xb, N * 16);
  int nb1 = (M + 255) / 256;
  scan_blk<<<nb1, 256, 0, stream>>>(hist, hist, bsum, M);
  scan_top<<<1, 512, 0, stream>>>(bsum, nb1);
  scan_add<<<nb1, 256, 0, stream>>>(hist, bsum, M);
  scatter_kernel<<<NBLKB, 1024, NB * 4, stream>>>(src, dst, hist, binned, E, NB);
  fine_kernel<<<NB, 256, 0, stream>>>(binned, hist, rowptr, col, E, NB, NBLKB, N);

  int ab = (N * 8 + 255) / 256;  // 32 nodes per 256-thread block

  // layer 1
  agg_kernel<<<ab, 256, 0, stream>>>(xb, rowptr, col, hmb, N);
  gemm_stream<<<gblk, 256, 0, stream>>>(xb, hmb, Ws1, Wn1, b1, zb, partial, N, ntiles);
  reduce_stats<<<128, 256, 0, stream>>>(partial, stats1, gblk);
  bn_bf16_kernel<<<2048, 256, 0, stream>>>(zb, stats1, g1, be1, h1b, N);

  // layer 2
  agg_kernel<<<ab, 256, 0, stream>>>(h1b, rowptr, col, hmb, N);
  gemm_stream<<<gblk, 256, 0, stream>>>(h1b, hmb, Ws2, Wn2, b2, zb, partial, N, ntiles);
  reduce_stats<<<128, 256, 0, stream>>>(partial, stats2, gblk);
  bn_f32_kernel<<<2048, 256, 0, stream>>>(zb, stats2, g2, be2, out, N);
}